// Round 1
// baseline (3183.998 us; speedup 1.0000x reference)
//
#include <hip/hip_runtime.h>

// FiLM forward == fixed linear map K (192x768) applied to inputs (8,768,64), K rebuilt
// on-device each call from spec weights + HiPPO-LegT constants.
// ws layout (total ~51.4 MB):
//   Mf64[3][256][256] f64, Ya/Yb/Z f64 (Newton), W0/W1 f32 [3][256][512] (GJ aug ping-pong),
//   E f32 [3][256][256], AP0/AP1 f32 (Ad power ping-pong), Bd, V f32 [3][768][256],
//   em f32 [3][192][256], P f32 [1344][256], K f32 [192][768],
//   Wt f32 [3][256][4096] (per-mode-chunk weights), U f32 [1344][4096].

#define OFF_MF64  0
#define OFF_YA    1572864
#define OFF_YB    3145728
#define OFF_Z     4718592
#define OFF_W0    6291456
#define OFF_W1    7864320
#define OFF_E     9437184
#define OFF_AP0   10223616
#define OFF_AP1   11010048
#define OFF_BD    11796480
#define OFF_V     11800576
#define OFF_EM    14159872
#define OFF_P     14749696
#define OFF_K     16125952
#define OFF_WT    16715776
#define OFF_U     29298688

__device__ __forceinline__ double a_entry(int i, int j){
  double base = (i < j) ? -1.0 : (((i - j) & 1) ? 1.0 : -1.0);  // (-1)^(i-j+1) for i>=j
  return base * (double)(2*i + 1);
}

// Build Mf64 = I - dt/2*A  and GJ working buffer W0 = [M_f32 | I]
__global__ void k_init(double* __restrict__ Mf64, float* __restrict__ W0){
  int s = blockIdx.y, i = blockIdx.x, j = threadIdx.x;
  double dt = (1.0 / 192.0) / (double)(1 << s);
  double m = ((i == j) ? 1.0 : 0.0) - 0.5 * dt * a_entry(i, j);
  Mf64[((size_t)s*256 + i)*256 + j] = m;
  float* w = W0 + ((size_t)s*256 + i)*512;
  w[j] = (float)m;
  w[256 + j] = (i == j) ? 1.0f : 0.0f;
}

// Blocked f32 Gauss-Jordan, panel of 32 cols in LDS, row-op matrix E (256x256) in registers.
__global__ __launch_bounds__(1024) void k_panel(const float* __restrict__ bufIn,
                                                float* __restrict__ Ebuf, int kpanel){
  int s = blockIdx.x;
  const float* buf = bufIn + (size_t)s*256*512;
  float* Eout = Ebuf + (size_t)s*65536;
  __shared__ float pan[256][33];     // +1 pad: avoid 16-way bank conflicts
  __shared__ float fac[256];
  __shared__ float eprow[256];
  __shared__ float prow[32];
  __shared__ float rv[256];
  __shared__ int   ridx[256];
  __shared__ float swA[256], swB[256];
  int tid = threadIdx.x;
  int r = tid >> 2, g = tid & 3;
  int c0 = kpanel * 32;
  for (int q = 0; q < 8; ++q) pan[r][g*8 + q] = buf[(size_t)r*512 + c0 + g*8 + q];
  float E[64];
  #pragma unroll
  for (int c = 0; c < 64; ++c) E[c] = (r == g*64 + c) ? 1.0f : 0.0f;
  __syncthreads();
  for (int l = 0; l < 32; ++l){
    int p = c0 + l;
    if (tid < 256){
      rv[tid] = (tid >= p) ? fabsf(pan[tid][l]) : -1.0f;
      ridx[tid] = tid;
    }
    __syncthreads();
    for (int off = 128; off > 0; off >>= 1){
      if (tid < off){
        if (rv[tid+off] > rv[tid] || (rv[tid+off] == rv[tid] && ridx[tid+off] < ridx[tid])){
          rv[tid] = rv[tid+off]; ridx[tid] = ridx[tid+off];
        }
      }
      __syncthreads();
    }
    int piv = ridx[0];
    if (piv != p){
      if (tid < 32){ float a = pan[p][tid]; pan[p][tid] = pan[piv][tid]; pan[piv][tid] = a; }
      if (r == p){
        #pragma unroll
        for (int c = 0; c < 64; ++c) swA[g*64 + c] = E[c];
      }
      if (r == piv){
        #pragma unroll
        for (int c = 0; c < 64; ++c) swB[g*64 + c] = E[c];
      }
      __syncthreads();
      if (r == p){
        #pragma unroll
        for (int c = 0; c < 64; ++c) E[c] = swB[g*64 + c];
      }
      if (r == piv){
        #pragma unroll
        for (int c = 0; c < 64; ++c) E[c] = swA[g*64 + c];
      }
    }
    __syncthreads();
    float invp = 1.0f / pan[p][l];
    if (r == p){
      #pragma unroll
      for (int c = 0; c < 64; ++c){ E[c] *= invp; eprow[g*64 + c] = E[c]; }
    }
    if (tid < 32){ pan[p][tid] *= invp; prow[tid] = pan[p][tid]; }
    if (tid < 256) fac[tid] = pan[tid][l];   // fac[p] unused
    __syncthreads();
    float f = fac[r];
    if (r != p){
      #pragma unroll
      for (int q = 0; q < 8; ++q){ int c = g*8 + q; pan[r][c] -= f * prow[c]; }
      #pragma unroll
      for (int c = 0; c < 64; ++c) E[c] -= f * eprow[g*64 + c];
    }
    __syncthreads();
  }
  #pragma unroll
  for (int c = 0; c < 64; ++c) Eout[(size_t)r*256 + g*64 + c] = E[c];
}

// Trailing update: bufOut[:, c>=32*(k+1)] = E @ bufIn
__global__ void k_trail(const float* __restrict__ bufIn, float* __restrict__ bufOut,
                        const float* __restrict__ Ebuf, int kpanel){
  int s = blockIdx.z;
  const float* in = bufIn + (size_t)s*131072;
  float* out = bufOut + (size_t)s*131072;
  const float* E = Ebuf + (size_t)s*65536;
  int c = (kpanel+1)*32 + blockIdx.x*256 + threadIdx.x;
  if (c >= 512) return;
  int r0 = blockIdx.y * 8;
  float acc[8] = {0,0,0,0,0,0,0,0};
  for (int j = 0; j < 256; ++j){
    float v = in[(size_t)j*512 + c];
    #pragma unroll
    for (int q = 0; q < 8; ++q) acc[q] += E[(size_t)(r0+q)*256 + j] * v;
  }
  #pragma unroll
  for (int q = 0; q < 8; ++q) out[(size_t)(r0+q)*512 + c] = acc[q];
}

__global__ void k_y0(const float* __restrict__ W, double* __restrict__ Y){
  int s = blockIdx.y, i = blockIdx.x, j = threadIdx.x;
  Y[((size_t)s*256 + i)*256 + j] = (double)W[((size_t)s*256 + i)*512 + 256 + j];
}

// Z = M @ Y  (f64)
__global__ void k_mmZ(const double* __restrict__ M, const double* __restrict__ Y,
                      double* __restrict__ Z){
  int s = blockIdx.y;
  const double* A = M + (size_t)s*65536;
  const double* B = Y + (size_t)s*65536;
  int c = threadIdx.x, r0 = blockIdx.x * 8;
  double acc[8] = {0,0,0,0,0,0,0,0};
  for (int j = 0; j < 256; ++j){
    double b = B[(size_t)j*256 + c];
    #pragma unroll
    for (int q = 0; q < 8; ++q) acc[q] += A[(size_t)(r0+q)*256 + j] * b;
  }
  #pragma unroll
  for (int q = 0; q < 8; ++q) Z[(size_t)s*65536 + (size_t)(r0+q)*256 + c] = acc[q];
}

// Yn = 2Y - Y @ Z  (Newton-Schulz step, f64)
__global__ void k_mmN(const double* __restrict__ Y, const double* __restrict__ Z,
                      double* __restrict__ Yn){
  int s = blockIdx.y;
  const double* A = Y + (size_t)s*65536;
  const double* B = Z + (size_t)s*65536;
  int c = threadIdx.x, r0 = blockIdx.x * 8;
  double acc[8] = {0,0,0,0,0,0,0,0};
  for (int j = 0; j < 256; ++j){
    double b = B[(size_t)j*256 + c];
    #pragma unroll
    for (int q = 0; q < 8; ++q) acc[q] += A[(size_t)(r0+q)*256 + j] * b;
  }
  #pragma unroll
  for (int q = 0; q < 8; ++q)
    Yn[(size_t)s*65536 + (size_t)(r0+q)*256 + c] =
      2.0 * A[(size_t)(r0+q)*256 + c] - acc[q];
}

// Ad = 2*Minv - I (f32, into AP0); Bd = Minv @ (dt*B); V row0 = Bd
__global__ void k_final(const double* __restrict__ Y, float* __restrict__ Ad,
                        float* __restrict__ Bd, float* __restrict__ V){
  int s = blockIdx.y;
  const double* Ys = Y + (size_t)s*65536;
  if (blockIdx.x < 64){
    int c = threadIdx.x, r0 = blockIdx.x * 4;
    #pragma unroll
    for (int q = 0; q < 4; ++q){
      double v = 2.0 * Ys[(size_t)(r0+q)*256 + c] - ((r0+q) == c ? 1.0 : 0.0);
      Ad[(size_t)s*65536 + (size_t)(r0+q)*256 + c] = (float)v;
    }
  } else {
    int i = threadIdx.x;
    double dt = (1.0 / 192.0) / (double)(1 << s);
    double acc = 0.0;
    for (int j = 0; j < 256; ++j){
      double bj = dt * ((j & 1) ? -1.0 : 1.0) * (double)(2*j + 1);
      acc += Ys[(size_t)i*256 + j] * bj;
    }
    float b = (float)acc;
    Bd[s*256 + i] = b;
    V[((size_t)s*768 + 0)*256 + i] = b;
  }
}

// Legendre eval matrix (last 192 rows), f64 recurrence
__global__ void k_em(float* __restrict__ em){
  int s = blockIdx.x, t = threadIdx.x;
  int T = 192 << s;
  double dt = (1.0 / 192.0) / (double)(1 << s);
  double x = 1.0 - 2.0 * ((double)(T - 192 + t) * dt);
  float* row = em + ((size_t)s*192 + t)*256;
  double p0 = 1.0, p1 = x;
  row[0] = 1.0f; row[1] = (float)x;
  for (int n = 1; n < 255; ++n){
    double p2 = ((double)(2*n+1) * x * p1 - (double)n * p0) / (double)(n+1);
    row[n+1] = (float)p2;
    p0 = p1; p1 = p2;
  }
}

// one doubling level: Pout = Pin@Pin (bx<64); V[L..2L) = Pin @ V[0..L)  (bx>=64)
__global__ void k_level(const float* __restrict__ Pin, float* __restrict__ Pout,
                        float* __restrict__ V, int L){
  int s = blockIdx.y;
  const float* A = Pin + (size_t)s*65536;
  int bx = blockIdx.x;
  if (bx < 64){
    int c = threadIdx.x, r0 = bx * 4;
    float acc[4] = {0,0,0,0};
    for (int k = 0; k < 256; ++k){
      float b = A[(size_t)k*256 + c];
      #pragma unroll
      for (int q = 0; q < 4; ++q) acc[q] += A[(size_t)(r0+q)*256 + k] * b;
    }
    #pragma unroll
    for (int q = 0; q < 4; ++q) Pout[(size_t)s*65536 + (size_t)(r0+q)*256 + c] = acc[q];
  } else {
    int j = threadIdx.x;
    if (j >= L) return;
    int r0 = (bx - 64) * 4;
    float* Vs = V + (size_t)s*768*256;
    float acc[4] = {0,0,0,0};
    for (int k = 0; k < 256; ++k){
      float v = Vs[(size_t)j*256 + k];
      #pragma unroll
      for (int q = 0; q < 4; ++q) acc[q] += A[(size_t)(r0+q)*256 + k] * v;
    }
    #pragma unroll
    for (int q = 0; q < 4; ++q) Vs[(size_t)(L+j)*256 + r0 + q] = acc[q];
  }
}

// V[128*jc + r] = A128 @ V[128*(jc-1) + r]
__global__ void k_chunk(const float* __restrict__ A128, float* __restrict__ V, int jc){
  int s = blockIdx.y;
  const float* A = A128 + (size_t)s*65536;
  float* Vs = V + (size_t)s*768*256;
  int r = threadIdx.x;          // 0..127
  int r0 = blockIdx.x * 4;
  const float* vin = Vs + (size_t)(128*(jc-1) + r)*256;
  float acc[4] = {0,0,0,0};
  for (int k = 0; k < 256; ++k){
    float v = vin[k];
    #pragma unroll
    for (int q = 0; q < 4; ++q) acc[q] += A[(size_t)(r0+q)*256 + k] * v;
  }
  #pragma unroll
  for (int q = 0; q < 4; ++q) Vs[(size_t)(128*jc + r)*256 + r0 + q] = acc[q];
}

// Wt[s][i][col] with col = (kl*2+ri)*256 + o,  k = c8+kl
__global__ void k_wt(const float* __restrict__ wr, const float* __restrict__ wi,
                     float* __restrict__ Wt, int c8){
  int s = blockIdx.x, i = blockIdx.y, tid = threadIdx.x;
  size_t srcbase = ((size_t)s*256 + i)*256;
  float* dst = Wt + ((size_t)s*256 + i)*4096;
  for (int ph = 0; ph < 16; ++ph){
    int col = ph*256 + tid;
    int kl = col >> 9, ri = (col >> 8) & 1, o = col & 255;
    const float* src = ri ? wi : wr;
    dst[col] = src[(srcbase + o)*32 + c8 + kl];
  }
}

// U = V @ Wt   (M in {192,384,768}, N=4096, K=256), 64x64 tiles, 4x4 per thread
__global__ __launch_bounds__(256) void k_ugemm(const float* __restrict__ V,
                                               const float* __restrict__ Wt,
                                               float* __restrict__ U){
  int s = blockIdx.z;
  int Ts = 192 << s;
  int mt = blockIdx.y;
  if (mt*64 >= Ts) return;
  int nt = blockIdx.x;
  __shared__ float As[16][68];
  __shared__ float Bs[16][68];
  const float* Vs = V + (size_t)s*768*256;
  const float* Bm = Wt + (size_t)s*256*4096;
  int tid = threadIdx.x;
  int tm = tid >> 4, tn = tid & 15;
  float acc[4][4];
  #pragma unroll
  for (int a = 0; a < 4; ++a)
    #pragma unroll
    for (int b = 0; b < 4; ++b) acc[a][b] = 0.0f;
  int arow = mt*64 + (tid >> 2);
  int acol4 = (tid & 3) * 4;
  int brow = tid >> 4;
  int bcol = nt*64 + (tid & 15)*4;
  for (int k0 = 0; k0 < 256; k0 += 16){
    float4 a4 = *(const float4*)&Vs[(size_t)arow*256 + k0 + acol4];
    float4 b4 = *(const float4*)&Bm[(size_t)(k0 + brow)*4096 + bcol];
    As[acol4+0][tid>>2] = a4.x; As[acol4+1][tid>>2] = a4.y;
    As[acol4+2][tid>>2] = a4.z; As[acol4+3][tid>>2] = a4.w;
    *(float4*)&Bs[brow][(tid & 15)*4] = b4;
    __syncthreads();
    #pragma unroll
    for (int k = 0; k < 16; ++k){
      float av[4], bv[4];
      *(float4*)av = *(const float4*)&As[k][tm*4];
      *(float4*)bv = *(const float4*)&Bs[k][tn*4];
      #pragma unroll
      for (int a = 0; a < 4; ++a)
        #pragma unroll
        for (int b = 0; b < 4; ++b) acc[a][b] += av[a]*bv[b];
    }
    __syncthreads();
  }
  int ub = (s == 0) ? 0 : (s == 1 ? 192 : 576);
  size_t out0 = ((size_t)(ub + mt*64 + tm*4))*4096 + nt*64 + tn*4;
  #pragma unroll
  for (int a = 0; a < 4; ++a){
    float4 o4 = make_float4(acc[a][0], acc[a][1], acc[a][2], acc[a][3]);
    *(float4*)&U[out0 + (size_t)a*4096] = o4;
  }
}

// modulated prefix scan over U, rotate, accumulate into P
__global__ void k_scan(const float* __restrict__ U, float* __restrict__ P, int c8){
  int s = blockIdx.y;
  int kl = blockIdx.x;
  int k = c8 + kl;
  int T = 192 << s;
  int ub = (s == 0) ? 0 : (s == 1 ? 192 : 576);
  int o = threadIdx.x;
  const float* Ub = U + (size_t)ub*4096 + kl*512 + o;
  float* Pb = P + (size_t)ub*256 + o;
  float Zr = 0.f, Zi = 0.f;
  float ckT = ((k == 0) ? 1.0f : 2.0f) / (float)T;
  int im = 0;
  int ib = (k * 192) % T;   // (k*(m+192)) mod T at m=0
  float th = 6.283185307179586f / (float)T;
  #pragma unroll 2
  for (int m = 0; m < T; ++m){
    float ur = Ub[(size_t)m*4096];
    float ui = Ub[(size_t)m*4096 + 256];
    float sa, ca; __sincosf(th * (float)im, &sa, &ca);   // e^{-i*ang}
    Zr += ca*ur + sa*ui;
    Zi += ca*ui - sa*ur;
    float sb, cb; __sincosf(th * (float)ib, &sb, &cb);   // e^{+i*beta}
    atomicAdd(&Pb[(size_t)(T-1-m)*256], ckT * (Zr*cb - Zi*sb));
    im += k; if (im >= T) im -= T;
    ib += k; if (ib >= T) ib -= T;
  }
}

// K[to][tg] = sum_s mlpw[s] * sum_o em[s][to][o] * P[s][tg-off][o]
__global__ void k_K(const float* __restrict__ em, const float* __restrict__ P,
                    const float* __restrict__ mlpw, float* __restrict__ K){
  int to = blockIdx.y;
  int tg = blockIdx.x*64 + threadIdx.x;
  float acc = 0.f;
  for (int s = 0; s < 3; ++s){
    int T = 192 << s;
    int off = 768 - T;
    if (tg >= off){
      int ub = (s == 0) ? 0 : (s == 1 ? 192 : 576);
      const float* Pr = P + ((size_t)ub + (tg - off))*256;
      const float* er = em + ((size_t)s*192 + to)*256;
      float a = 0.f;
      for (int o2 = 0; o2 < 256; ++o2) a += er[o2] * Pr[o2];
      acc += mlpw[s] * a;
    }
  }
  K[(size_t)to*768 + tg] = acc;
}

// out[b][to][d] = mlp_b + sum_t K[to][t] * inputs[b][t][d]
__global__ void k_out(const float* __restrict__ K, const float* __restrict__ inp,
                      const float* __restrict__ mlpb, float* __restrict__ out){
  int to = blockIdx.x, b = blockIdx.y, d = threadIdx.x;
  const float* Kr = K + (size_t)to*768;
  const float* ip = inp + (size_t)b*768*64 + d;
  float acc = mlpb[0];
  #pragma unroll 4
  for (int t = 0; t < 768; ++t) acc += Kr[t] * ip[(size_t)t*64];
  out[((size_t)b*192 + to)*64 + d] = acc;
}

extern "C" void kernel_launch(void* const* d_in, const int* in_sizes, int n_in,
                              void* d_out, int out_size, void* d_ws, size_t ws_size,
                              hipStream_t stream){
  const float* inputs  = (const float*)d_in[0];
  const float* spec_wr = (const float*)d_in[1];
  const float* spec_wi = (const float*)d_in[2];
  const float* mlp_w   = (const float*)d_in[3];
  const float* mlp_b   = (const float*)d_in[4];
  float* out = (float*)d_out;
  char* ws = (char*)d_ws;

  double* Mf64 = (double*)(ws + OFF_MF64);
  double* Ya   = (double*)(ws + OFF_YA);
  double* Yb   = (double*)(ws + OFF_YB);
  double* Zb   = (double*)(ws + OFF_Z);
  float* W0  = (float*)(ws + OFF_W0);
  float* W1  = (float*)(ws + OFF_W1);
  float* Eb  = (float*)(ws + OFF_E);
  float* AP0 = (float*)(ws + OFF_AP0);
  float* AP1 = (float*)(ws + OFF_AP1);
  float* Bd  = (float*)(ws + OFF_BD);
  float* V   = (float*)(ws + OFF_V);
  float* em  = (float*)(ws + OFF_EM);
  float* P   = (float*)(ws + OFF_P);
  float* Km  = (float*)(ws + OFF_K);
  float* Wt  = (float*)(ws + OFF_WT);
  float* U   = (float*)(ws + OFF_U);

  k_init<<<dim3(256,3), 256, 0, stream>>>(Mf64, W0);

  for (int kp = 0; kp < 8; ++kp){
    float* bin  = (kp & 1) ? W1 : W0;
    float* bout = (kp & 1) ? W0 : W1;
    k_panel<<<3, 1024, 0, stream>>>(bin, Eb, kp);
    k_trail<<<dim3(2,32,3), 256, 0, stream>>>(bin, bout, Eb, kp);
  }
  // Minv (f32) now in W0 right half
  k_y0<<<dim3(256,3), 256, 0, stream>>>(W0, Ya);
  for (int it = 0; it < 4; ++it){
    double* yi = (it & 1) ? Yb : Ya;
    double* yo = (it & 1) ? Ya : Yb;
    k_mmZ<<<dim3(32,3), 256, 0, stream>>>(Mf64, yi, Zb);
    k_mmN<<<dim3(32,3), 256, 0, stream>>>(yi, Zb, yo);
  }
  // refined Minv in Ya
  k_final<<<dim3(65,3), 256, 0, stream>>>(Ya, AP0, Bd, V);
  k_em<<<3, 192, 0, stream>>>(em);

  float* pin = AP0; float* pout = AP1;
  for (int L = 1; L <= 64; L <<= 1){
    k_level<<<dim3(128,3), 256, 0, stream>>>(pin, pout, V, L);
    float* t = pin; pin = pout; pout = t;
  }
  for (int jc = 1; jc <= 5; ++jc)
    k_chunk<<<dim3(64,3), 128, 0, stream>>>(pin, V, jc);

  hipMemsetAsync(P, 0, 1376256, stream);
  for (int c = 0; c < 4; ++c){
    k_wt<<<dim3(3,256), 256, 0, stream>>>(spec_wr, spec_wi, Wt, c*8);
    k_ugemm<<<dim3(64,12,3), 256, 0, stream>>>(V, Wt, U);
    k_scan<<<dim3(8,3), 256, 0, stream>>>(U, P, c*8);
  }
  k_K<<<dim3(12,192), 64, 0, stream>>>(em, P, mlp_w, Km);
  k_out<<<dim3(192,8), 64, 0, stream>>>(Km, inputs, mlp_b, out);
}

// Round 2
// 2235.119 us; speedup vs baseline: 1.4245x; 1.4245x over previous
//
#include <hip/hip_runtime.h>

// FiLM forward == fixed linear map K (192x768) applied to inputs (8,768,64), K rebuilt
// on-device each call from spec weights + HiPPO-LegT constants.
// Chunk-phase scratch C8/Seg alias the (dead by then) GJ/Newton/AP regions.

#define OFF_MF64  0
#define OFF_YA    1572864
#define OFF_YB    3145728
#define OFF_Z     4718592
#define OFF_W0    6291456
#define OFF_W1    7864320
#define OFF_E     9437184
#define OFF_AP0   10223616
#define OFF_AP1   11010048
#define OFF_BD    11796480
#define OFF_V     11800576
#define OFF_EM    14159872
#define OFF_P     14749696
#define OFF_K     16125952
#define OFF_WT    16715776
#define OFF_U     29298688
// aliases (live only during chunk phase; GJ/Newton/AP dead by then)
#define OFF_C8    0
#define OFF_SEG   11010048

__device__ __forceinline__ double a_entry(int i, int j){
  double base = (i < j) ? -1.0 : (((i - j) & 1) ? 1.0 : -1.0);  // (-1)^(i-j+1) for i>=j
  return base * (double)(2*i + 1);
}

// Build Mf64 = I - dt/2*A  and GJ working buffer W0 = [M_f32 | I]
__global__ void k_init(double* __restrict__ Mf64, float* __restrict__ W0){
  int s = blockIdx.y, i = blockIdx.x, j = threadIdx.x;
  double dt = (1.0 / 192.0) / (double)(1 << s);
  double m = ((i == j) ? 1.0 : 0.0) - 0.5 * dt * a_entry(i, j);
  Mf64[((size_t)s*256 + i)*256 + j] = m;
  float* w = W0 + ((size_t)s*256 + i)*512;
  w[j] = (float)m;
  w[256 + j] = (i == j) ? 1.0f : 0.0f;
}

// Blocked f32 Gauss-Jordan, panel of 32 cols in LDS, row-op matrix E (256x256) in registers.
__global__ __launch_bounds__(1024) void k_panel(const float* __restrict__ bufIn,
                                                float* __restrict__ Ebuf, int kpanel){
  int s = blockIdx.x;
  const float* buf = bufIn + (size_t)s*256*512;
  float* Eout = Ebuf + (size_t)s*65536;
  __shared__ float pan[256][33];     // +1 pad: avoid 16-way bank conflicts
  __shared__ float fac[256];
  __shared__ float eprow[256];
  __shared__ float prow[32];
  __shared__ float rv[256];
  __shared__ int   ridx[256];
  __shared__ float swA[256], swB[256];
  int tid = threadIdx.x;
  int r = tid >> 2, g = tid & 3;
  int c0 = kpanel * 32;
  for (int q = 0; q < 8; ++q) pan[r][g*8 + q] = buf[(size_t)r*512 + c0 + g*8 + q];
  float E[64];
  #pragma unroll
  for (int c = 0; c < 64; ++c) E[c] = (r == g*64 + c) ? 1.0f : 0.0f;
  __syncthreads();
  for (int l = 0; l < 32; ++l){
    int p = c0 + l;
    if (tid < 256){
      rv[tid] = (tid >= p) ? fabsf(pan[tid][l]) : -1.0f;
      ridx[tid] = tid;
    }
    __syncthreads();
    for (int off = 128; off > 0; off >>= 1){
      if (tid < off){
        if (rv[tid+off] > rv[tid] || (rv[tid+off] == rv[tid] && ridx[tid+off] < ridx[tid])){
          rv[tid] = rv[tid+off]; ridx[tid] = ridx[tid+off];
        }
      }
      __syncthreads();
    }
    int piv = ridx[0];
    if (piv != p){
      if (tid < 32){ float a = pan[p][tid]; pan[p][tid] = pan[piv][tid]; pan[piv][tid] = a; }
      if (r == p){
        #pragma unroll
        for (int c = 0; c < 64; ++c) swA[g*64 + c] = E[c];
      }
      if (r == piv){
        #pragma unroll
        for (int c = 0; c < 64; ++c) swB[g*64 + c] = E[c];
      }
      __syncthreads();
      if (r == p){
        #pragma unroll
        for (int c = 0; c < 64; ++c) E[c] = swB[g*64 + c];
      }
      if (r == piv){
        #pragma unroll
        for (int c = 0; c < 64; ++c) E[c] = swA[g*64 + c];
      }
    }
    __syncthreads();
    float invp = 1.0f / pan[p][l];
    if (r == p){
      #pragma unroll
      for (int c = 0; c < 64; ++c){ E[c] *= invp; eprow[g*64 + c] = E[c]; }
    }
    if (tid < 32){ pan[p][tid] *= invp; prow[tid] = pan[p][tid]; }
    if (tid < 256) fac[tid] = pan[tid][l];   // fac[p] unused
    __syncthreads();
    float f = fac[r];
    if (r != p){
      #pragma unroll
      for (int q = 0; q < 8; ++q){ int c = g*8 + q; pan[r][c] -= f * prow[c]; }
      #pragma unroll
      for (int c = 0; c < 64; ++c) E[c] -= f * eprow[g*64 + c];
    }
    __syncthreads();
  }
  #pragma unroll
  for (int c = 0; c < 64; ++c) Eout[(size_t)r*256 + g*64 + c] = E[c];
}

// Trailing update: bufOut[:, c>=32*(k+1)] = E @ bufIn
__global__ void k_trail(const float* __restrict__ bufIn, float* __restrict__ bufOut,
                        const float* __restrict__ Ebuf, int kpanel){
  int s = blockIdx.z;
  const float* in = bufIn + (size_t)s*131072;
  float* out = bufOut + (size_t)s*131072;
  const float* E = Ebuf + (size_t)s*65536;
  int c = (kpanel+1)*32 + blockIdx.x*256 + threadIdx.x;
  if (c >= 512) return;
  int r0 = blockIdx.y * 8;
  float acc[8] = {0,0,0,0,0,0,0,0};
  for (int j = 0; j < 256; ++j){
    float v = in[(size_t)j*512 + c];
    #pragma unroll
    for (int q = 0; q < 8; ++q) acc[q] += E[(size_t)(r0+q)*256 + j] * v;
  }
  #pragma unroll
  for (int q = 0; q < 8; ++q) out[(size_t)(r0+q)*512 + c] = acc[q];
}

__global__ void k_y0(const float* __restrict__ W, double* __restrict__ Y){
  int s = blockIdx.y, i = blockIdx.x, j = threadIdx.x;
  Y[((size_t)s*256 + i)*256 + j] = (double)W[((size_t)s*256 + i)*512 + 256 + j];
}

// Z = M @ Y  (f64)
__global__ void k_mmZ(const double* __restrict__ M, const double* __restrict__ Y,
                      double* __restrict__ Z){
  int s = blockIdx.y;
  const double* A = M + (size_t)s*65536;
  const double* B = Y + (size_t)s*65536;
  int c = threadIdx.x, r0 = blockIdx.x * 8;
  double acc[8] = {0,0,0,0,0,0,0,0};
  for (int j = 0; j < 256; ++j){
    double b = B[(size_t)j*256 + c];
    #pragma unroll
    for (int q = 0; q < 8; ++q) acc[q] += A[(size_t)(r0+q)*256 + j] * b;
  }
  #pragma unroll
  for (int q = 0; q < 8; ++q) Z[(size_t)s*65536 + (size_t)(r0+q)*256 + c] = acc[q];
}

// Yn = 2Y - Y @ Z  (Newton-Schulz step, f64)
__global__ void k_mmN(const double* __restrict__ Y, const double* __restrict__ Z,
                      double* __restrict__ Yn){
  int s = blockIdx.y;
  const double* A = Y + (size_t)s*65536;
  const double* B = Z + (size_t)s*65536;
  int c = threadIdx.x, r0 = blockIdx.x * 8;
  double acc[8] = {0,0,0,0,0,0,0,0};
  for (int j = 0; j < 256; ++j){
    double b = B[(size_t)j*256 + c];
    #pragma unroll
    for (int q = 0; q < 8; ++q) acc[q] += A[(size_t)(r0+q)*256 + j] * b;
  }
  #pragma unroll
  for (int q = 0; q < 8; ++q)
    Yn[(size_t)s*65536 + (size_t)(r0+q)*256 + c] =
      2.0 * A[(size_t)(r0+q)*256 + c] - acc[q];
}

// Ad = 2*Minv - I (f32, into AP0); Bd = Minv @ (dt*B); V row0 = Bd
__global__ void k_final(const double* __restrict__ Y, float* __restrict__ Ad,
                        float* __restrict__ Bd, float* __restrict__ V){
  int s = blockIdx.y;
  const double* Ys = Y + (size_t)s*65536;
  if (blockIdx.x < 64){
    int c = threadIdx.x, r0 = blockIdx.x * 4;
    #pragma unroll
    for (int q = 0; q < 4; ++q){
      double v = 2.0 * Ys[(size_t)(r0+q)*256 + c] - ((r0+q) == c ? 1.0 : 0.0);
      Ad[(size_t)s*65536 + (size_t)(r0+q)*256 + c] = (float)v;
    }
  } else {
    int i = threadIdx.x;
    double dt = (1.0 / 192.0) / (double)(1 << s);
    double acc = 0.0;
    for (int j = 0; j < 256; ++j){
      double bj = dt * ((j & 1) ? -1.0 : 1.0) * (double)(2*j + 1);
      acc += Ys[(size_t)i*256 + j] * bj;
    }
    float b = (float)acc;
    Bd[s*256 + i] = b;
    V[((size_t)s*768 + 0)*256 + i] = b;
  }
}

// Legendre eval matrix (last 192 rows), f64 recurrence
__global__ void k_em(float* __restrict__ em){
  int s = blockIdx.x, t = threadIdx.x;
  int T = 192 << s;
  double dt = (1.0 / 192.0) / (double)(1 << s);
  double x = 1.0 - 2.0 * ((double)(T - 192 + t) * dt);
  float* row = em + ((size_t)s*192 + t)*256;
  double p0 = 1.0, p1 = x;
  row[0] = 1.0f; row[1] = (float)x;
  for (int n = 1; n < 255; ++n){
    double p2 = ((double)(2*n+1) * x * p1 - (double)n * p0) / (double)(n+1);
    row[n+1] = (float)p2;
    p0 = p1; p1 = p2;
  }
}

// one doubling level: Pout = Pin@Pin (bx<64); V[L..2L) = Pin @ V[0..L)  (bx>=64)
__global__ void k_level(const float* __restrict__ Pin, float* __restrict__ Pout,
                        float* __restrict__ V, int L){
  int s = blockIdx.y;
  const float* A = Pin + (size_t)s*65536;
  int bx = blockIdx.x;
  if (bx < 64){
    int c = threadIdx.x, r0 = bx * 4;
    float acc[4] = {0,0,0,0};
    for (int k = 0; k < 256; ++k){
      float b = A[(size_t)k*256 + c];
      #pragma unroll
      for (int q = 0; q < 4; ++q) acc[q] += A[(size_t)(r0+q)*256 + k] * b;
    }
    #pragma unroll
    for (int q = 0; q < 4; ++q) Pout[(size_t)s*65536 + (size_t)(r0+q)*256 + c] = acc[q];
  } else {
    int j = threadIdx.x;
    if (j >= L) return;
    int r0 = (bx - 64) * 4;
    float* Vs = V + (size_t)s*768*256;
    float acc[4] = {0,0,0,0};
    for (int k = 0; k < 256; ++k){
      float v = Vs[(size_t)j*256 + k];
      #pragma unroll
      for (int q = 0; q < 4; ++q) acc[q] += A[(size_t)(r0+q)*256 + k] * v;
    }
    #pragma unroll
    for (int q = 0; q < 4; ++q) Vs[(size_t)(L+j)*256 + r0 + q] = acc[q];
  }
}

// V[128*jc + r] = A128 @ V[128*(jc-1) + r]
__global__ void k_chunk(const float* __restrict__ A128, float* __restrict__ V, int jc){
  int s = blockIdx.y;
  const float* A = A128 + (size_t)s*65536;
  float* Vs = V + (size_t)s*768*256;
  int r = threadIdx.x;          // 0..127
  int r0 = blockIdx.x * 4;
  const float* vin = Vs + (size_t)(128*(jc-1) + r)*256;
  float acc[4] = {0,0,0,0};
  for (int k = 0; k < 256; ++k){
    float v = vin[k];
    #pragma unroll
    for (int q = 0; q < 4; ++q) acc[q] += A[(size_t)(r0+q)*256 + k] * v;
  }
  #pragma unroll
  for (int q = 0; q < 4; ++q) Vs[(size_t)(128*jc + r)*256 + r0 + q] = acc[q];
}

// Wt[s][i][col] with col = (kl*2+ri)*256 + o,  k = c8+kl
__global__ void k_wt(const float* __restrict__ wr, const float* __restrict__ wi,
                     float* __restrict__ Wt, int c8){
  int s = blockIdx.x, i = blockIdx.y, tid = threadIdx.x;
  size_t srcbase = ((size_t)s*256 + i)*256;
  float* dst = Wt + ((size_t)s*256 + i)*4096;
  for (int ph = 0; ph < 16; ++ph){
    int col = ph*256 + tid;
    int kl = col >> 9, ri = (col >> 8) & 1, o = col & 255;
    const float* src = ri ? wi : wr;
    dst[col] = src[(srcbase + o)*32 + c8 + kl];
  }
}

// U = V @ Wt   (M in {192,384,768}, N=4096, K=256), 64x64 tiles, 4x4 per thread
__global__ __launch_bounds__(256) void k_ugemm(const float* __restrict__ V,
                                               const float* __restrict__ Wt,
                                               float* __restrict__ U){
  int s = blockIdx.z;
  int Ts = 192 << s;
  int mt = blockIdx.y;
  if (mt*64 >= Ts) return;
  int nt = blockIdx.x;
  __shared__ float As[16][68];
  __shared__ float Bs[16][68];
  const float* Vs = V + (size_t)s*768*256;
  const float* Bm = Wt + (size_t)s*256*4096;
  int tid = threadIdx.x;
  int tm = tid >> 4, tn = tid & 15;
  float acc[4][4];
  #pragma unroll
  for (int a = 0; a < 4; ++a)
    #pragma unroll
    for (int b = 0; b < 4; ++b) acc[a][b] = 0.0f;
  int arow = mt*64 + (tid >> 2);
  int acol4 = (tid & 3) * 4;
  int brow = tid >> 4;
  int bcol = nt*64 + (tid & 15)*4;
  for (int k0 = 0; k0 < 256; k0 += 16){
    float4 a4 = *(const float4*)&Vs[(size_t)arow*256 + k0 + acol4];
    float4 b4 = *(const float4*)&Bm[(size_t)(k0 + brow)*4096 + bcol];
    As[acol4+0][tid>>2] = a4.x; As[acol4+1][tid>>2] = a4.y;
    As[acol4+2][tid>>2] = a4.z; As[acol4+3][tid>>2] = a4.w;
    *(float4*)&Bs[brow][(tid & 15)*4] = b4;
    __syncthreads();
    #pragma unroll
    for (int k = 0; k < 16; ++k){
      float av[4], bv[4];
      *(float4*)av = *(const float4*)&As[k][tm*4];
      *(float4*)bv = *(const float4*)&Bs[k][tn*4];
      #pragma unroll
      for (int a = 0; a < 4; ++a)
        #pragma unroll
        for (int b = 0; b < 4; ++b) acc[a][b] += av[a]*bv[b];
    }
    __syncthreads();
  }
  int ub = (s == 0) ? 0 : (s == 1 ? 192 : 576);
  size_t out0 = ((size_t)(ub + mt*64 + tm*4))*4096 + nt*64 + tn*4;
  #pragma unroll
  for (int a = 0; a < 4; ++a){
    float4 o4 = make_float4(acc[a][0], acc[a][1], acc[a][2], acc[a][3]);
    *(float4*)&U[out0 + (size_t)a*4096] = o4;
  }
}

// ---- two-phase parallel scan (replaces atomic k_scan) ----
// Phase A: per-segment local complex prefix (in place over U) + segment totals.
__global__ void k_scanA(float* __restrict__ U, float* __restrict__ Seg, int c8){
  int seg = blockIdx.x;      // 0..7
  int kl  = blockIdx.y;      // 0..7
  int s   = blockIdx.z;      // 0..2
  int k = c8 + kl;
  int T = 192 << s;
  int Ls = T >> 3;
  int m0 = seg * Ls;
  int ub = (s == 0) ? 0 : (s == 1 ? 192 : 576);
  int o = threadIdx.x;
  float* Ur = U + ((size_t)(ub + m0))*4096 + kl*512 + o;
  float th = 6.283185307179586f / (float)T;
  int im = (k * m0) % T;
  float Zr = 0.f, Zi = 0.f;
  #pragma unroll 4
  for (int i = 0; i < Ls; ++i){
    float ur = Ur[0];
    float ui = Ur[256];
    float sa, ca; __sincosf(th * (float)im, &sa, &ca);
    Zr += ca*ur + sa*ui;
    Zi += ca*ui - sa*ur;
    Ur[0] = Zr; Ur[256] = Zi;
    im += k; if (im >= T) im -= T;
    Ur += 4096;
  }
  float* Sg = Seg + (((size_t)(s*8 + kl)*8 + seg)*2)*256 + o;
  Sg[0] = Zr; Sg[256] = Zi;
}

// Phase C: add scanned segment offsets, rotate by e^{+i*2πk(192+m)/T}, write per-mode
// contribution to C8 (no atomics; each element written exactly once).
__global__ void k_scanC(const float* __restrict__ U, const float* __restrict__ Seg,
                        float* __restrict__ C8, int c8){
  int seg = blockIdx.x, kl = blockIdx.y, s = blockIdx.z;
  int k = c8 + kl;
  int T = 192 << s;
  int Ls = T >> 3;
  int m0 = seg * Ls;
  int ub = (s == 0) ? 0 : (s == 1 ? 192 : 576);
  int o = threadIdx.x;
  float offr = 0.f, offi = 0.f;
  const float* Sg = Seg + ((size_t)(s*8 + kl)*8)*512 + o;
  for (int j = 0; j < seg; ++j){ offr += Sg[(size_t)j*512]; offi += Sg[(size_t)j*512 + 256]; }
  const float* Ur = U + ((size_t)(ub + m0))*4096 + kl*512 + o;
  float* Cb = C8 + ((size_t)kl*1344 + ub)*256 + o;
  float ckT = ((k == 0) ? 1.0f : 2.0f) / (float)T;
  float th = 6.283185307179586f / (float)T;
  int ib = (k * (192 + m0)) % T;
  #pragma unroll 4
  for (int i = 0; i < Ls; ++i){
    int m = m0 + i;
    float zr = offr + Ur[0];
    float zi = offi + Ur[256];
    float sb, cb; __sincosf(th * (float)ib, &sb, &cb);
    Cb[(size_t)(T-1-m)*256] = ckT * (zr*cb - zi*sb);
    ib += k; if (ib >= T) ib -= T;
    Ur += 4096;
  }
}

// P[row][o] (+)= sum_kl C8[kl][row][o]
__global__ void k_reduce(const float* __restrict__ C8, float* __restrict__ P, int first){
  int row = blockIdx.x;    // 0..1343
  int o = threadIdx.x;
  float a = 0.f;
  #pragma unroll
  for (int kl = 0; kl < 8; ++kl) a += C8[((size_t)kl*1344 + row)*256 + o];
  size_t idx = (size_t)row*256 + o;
  if (first) P[idx] = a; else P[idx] += a;
}

// K[to][tg] = sum_s mlpw[s] * sum_o em[s][to][o] * P[s][tg-off][o]
__global__ void k_K(const float* __restrict__ em, const float* __restrict__ P,
                    const float* __restrict__ mlpw, float* __restrict__ K){
  int to = blockIdx.y;
  int tg = blockIdx.x*64 + threadIdx.x;
  float acc = 0.f;
  for (int s = 0; s < 3; ++s){
    int T = 192 << s;
    int off = 768 - T;
    if (tg >= off){
      int ub = (s == 0) ? 0 : (s == 1 ? 192 : 576);
      const float* Pr = P + ((size_t)ub + (tg - off))*256;
      const float* er = em + ((size_t)s*192 + to)*256;
      float a = 0.f;
      for (int o2 = 0; o2 < 256; ++o2) a += er[o2] * Pr[o2];
      acc += mlpw[s] * a;
    }
  }
  K[(size_t)to*768 + tg] = acc;
}

// out[b][to][d] = mlp_b + sum_t K[to][t] * inputs[b][t][d]
__global__ void k_out(const float* __restrict__ K, const float* __restrict__ inp,
                      const float* __restrict__ mlpb, float* __restrict__ out){
  int to = blockIdx.x, b = blockIdx.y, d = threadIdx.x;
  const float* Kr = K + (size_t)to*768;
  const float* ip = inp + (size_t)b*768*64 + d;
  float acc = mlpb[0];
  #pragma unroll 4
  for (int t = 0; t < 768; ++t) acc += Kr[t] * ip[(size_t)t*64];
  out[((size_t)b*192 + to)*64 + d] = acc;
}

extern "C" void kernel_launch(void* const* d_in, const int* in_sizes, int n_in,
                              void* d_out, int out_size, void* d_ws, size_t ws_size,
                              hipStream_t stream){
  const float* inputs  = (const float*)d_in[0];
  const float* spec_wr = (const float*)d_in[1];
  const float* spec_wi = (const float*)d_in[2];
  const float* mlp_w   = (const float*)d_in[3];
  const float* mlp_b   = (const float*)d_in[4];
  float* out = (float*)d_out;
  char* ws = (char*)d_ws;

  double* Mf64 = (double*)(ws + OFF_MF64);
  double* Ya   = (double*)(ws + OFF_YA);
  double* Yb   = (double*)(ws + OFF_YB);
  double* Zb   = (double*)(ws + OFF_Z);
  float* W0  = (float*)(ws + OFF_W0);
  float* W1  = (float*)(ws + OFF_W1);
  float* Eb  = (float*)(ws + OFF_E);
  float* AP0 = (float*)(ws + OFF_AP0);
  float* AP1 = (float*)(ws + OFF_AP1);
  float* Bd  = (float*)(ws + OFF_BD);
  float* V   = (float*)(ws + OFF_V);
  float* em  = (float*)(ws + OFF_EM);
  float* P   = (float*)(ws + OFF_P);
  float* Km  = (float*)(ws + OFF_K);
  float* Wt  = (float*)(ws + OFF_WT);
  float* U   = (float*)(ws + OFF_U);
  float* C8  = (float*)(ws + OFF_C8);
  float* Seg = (float*)(ws + OFF_SEG);

  k_init<<<dim3(256,3), 256, 0, stream>>>(Mf64, W0);

  for (int kp = 0; kp < 8; ++kp){
    float* bin  = (kp & 1) ? W1 : W0;
    float* bout = (kp & 1) ? W0 : W1;
    k_panel<<<3, 1024, 0, stream>>>(bin, Eb, kp);
    k_trail<<<dim3(2,32,3), 256, 0, stream>>>(bin, bout, Eb, kp);
  }
  // Minv (f32) now in W0 right half
  k_y0<<<dim3(256,3), 256, 0, stream>>>(W0, Ya);
  for (int it = 0; it < 3; ++it){
    double* yi = (it & 1) ? Yb : Ya;
    double* yo = (it & 1) ? Ya : Yb;
    k_mmZ<<<dim3(32,3), 256, 0, stream>>>(Mf64, yi, Zb);
    k_mmN<<<dim3(32,3), 256, 0, stream>>>(yi, Zb, yo);
  }
  // refined Minv in Yb (3 Newton iters: Ya->Yb->Ya->Yb)
  k_final<<<dim3(65,3), 256, 0, stream>>>(Yb, AP0, Bd, V);
  k_em<<<3, 192, 0, stream>>>(em);

  float* pin = AP0; float* pout = AP1;
  for (int L = 1; L <= 64; L <<= 1){
    k_level<<<dim3(128,3), 256, 0, stream>>>(pin, pout, V, L);
    float* t = pin; pin = pout; pout = t;
  }
  for (int jc = 1; jc <= 5; ++jc)
    k_chunk<<<dim3(64,3), 128, 0, stream>>>(pin, V, jc);

  for (int c = 0; c < 4; ++c){
    k_wt<<<dim3(3,256), 256, 0, stream>>>(spec_wr, spec_wi, Wt, c*8);
    k_ugemm<<<dim3(64,12,3), 256, 0, stream>>>(V, Wt, U);
    k_scanA<<<dim3(8,8,3), 256, 0, stream>>>(U, Seg, c*8);
    k_scanC<<<dim3(8,8,3), 256, 0, stream>>>(U, Seg, C8, c*8);
    k_reduce<<<1344, 256, 0, stream>>>(C8, P, (c == 0) ? 1 : 0);
  }
  k_K<<<dim3(12,192), 64, 0, stream>>>(em, P, mlp_w, Km);
  k_out<<<dim3(192,8), 64, 0, stream>>>(Km, inputs, mlp_b, out);
}

// Round 4
// 1415.833 us; speedup vs baseline: 2.2489x; 1.5787x over previous
//
#include <hip/hip_runtime.h>

// FiLM forward == fixed linear map K (192x768) applied to inputs (8,768,64), K rebuilt
// on-device each call from spec weights + HiPPO-LegT constants.
// Inversion: pivoted Gauss-Jordan (numerically required: LegT A is severely non-normal;
// Neumann/NS-from-scratch overflows f32 -- round-3 lesson), register-row panel +
// factor-replay trailing update, then 3 batched f64 Newton polish iterations.
// Chunk-phase scratch C8/Seg alias the (dead by then) inversion/AP regions.

#define OFF_MF64  0
#define OFF_YA    1572864
#define OFF_YB    3145728
#define OFF_Z     4718592
#define OFF_W0    6291456     // [3][256][512] f32 augmented [M | I], in-place GJ
#define OFF_F     7864320     // [3][32][256] f32 per-panel elementary factors
#define OFF_PIV   7962624     // [3][32] int pivots
#define OFF_AP0   10223616
#define OFF_AP1   11010048
#define OFF_BD    11796480
#define OFF_V     11800576
#define OFF_EM    14159872
#define OFF_P     14749696
#define OFF_K     16125952
#define OFF_WT    16715776
#define OFF_U     29298688
// aliases (live only during chunk phase; inversion/AP regions dead by then)
#define OFF_C8    0
#define OFF_SEG   11010048

__device__ __forceinline__ double a_entry(int i, int j){
  double base = (i < j) ? -1.0 : (((i - j) & 1) ? 1.0 : -1.0);  // (-1)^(i-j+1) for i>=j
  return base * (double)(2*i + 1);
}

// Build Mf64 = I - dt/2*A  and GJ working buffer W0 = [M_f32 | I]
__global__ void k_init(double* __restrict__ Mf64, float* __restrict__ W0){
  int s = blockIdx.y, i = blockIdx.x, j = threadIdx.x;
  double dt = (1.0 / 192.0) / (double)(1 << s);
  double m = ((i == j) ? 1.0 : 0.0) - 0.5 * dt * a_entry(i, j);
  Mf64[((size_t)s*256 + i)*256 + j] = m;
  float* w = W0 + ((size_t)s*256 + i)*512;
  w[j] = (float)m;
  w[256 + j] = (i == j) ? 1.0f : 0.0f;
}

// Panel factorization: pivoted GJ on 32-col panel, one row per thread in registers.
// Emits F[l][r] (F[l][p]=1/pivot, else elimination factor) and pivot indices.
__global__ __launch_bounds__(256) void k_panelF(float* __restrict__ W0,
                                                float* __restrict__ Fg,
                                                int* __restrict__ pivg, int kpanel){
  int s = blockIdx.x;
  float* buf = W0 + (size_t)s*131072;
  float* Fb = Fg + (size_t)s*8192;
  int* pivb = pivg + s*32;
  int r = threadIdx.x;
  int c0 = kpanel*32;
  float row[32];
  #pragma unroll
  for (int j = 0; j < 32; j += 4){
    float4 v = *(const float4*)&buf[(size_t)r*512 + c0 + j];
    row[j] = v.x; row[j+1] = v.y; row[j+2] = v.z; row[j+3] = v.w;
  }
  __shared__ float xA[32], xB[32], prow[32], wv[4], sInv;
  __shared__ int wi[4];
  #pragma unroll
  for (int l = 0; l < 32; ++l){
    int p = c0 + l;
    // ---- pivot search: argmax |row[l]| over rows >= p ----
    float a = (r >= p) ? fabsf(row[l]) : -1.0f;
    int bi = r;
    #pragma unroll
    for (int off = 32; off > 0; off >>= 1){
      float oa = __shfl_xor(a, off);
      int ob = __shfl_xor(bi, off);
      if (oa > a || (oa == a && ob < bi)){ a = oa; bi = ob; }
    }
    if ((r & 63) == 0){ wv[r >> 6] = a; wi[r >> 6] = bi; }
    __syncthreads();
    float best = wv[0]; int piv = wi[0];
    #pragma unroll
    for (int w = 1; w < 4; ++w){
      if (wv[w] > best || (wv[w] == best && wi[w] < piv)){ best = wv[w]; piv = wi[w]; }
    }
    // ---- swap rows p <-> piv (register rows exchanged via LDS) ----
    if (piv != p){
      if (r == p){
        #pragma unroll
        for (int j = 0; j < 32; ++j) xA[j] = row[j];
      }
      if (r == piv){
        #pragma unroll
        for (int j = 0; j < 32; ++j) xB[j] = row[j];
      }
      __syncthreads();
      if (r == p){
        #pragma unroll
        for (int j = 0; j < 32; ++j) row[j] = xB[j];
      }
      if (r == piv){
        #pragma unroll
        for (int j = 0; j < 32; ++j) row[j] = xA[j];
      }
    }
    // ---- scale pivot row, publish ----
    if (r == p){
      float inv = 1.0f / row[l];
      sInv = inv;
      #pragma unroll
      for (int j = 0; j < 32; ++j){ row[j] *= inv; prow[j] = row[j]; }
    }
    __syncthreads();
    float f = (r == p) ? 0.0f : row[l];
    Fb[l*256 + r] = (r == p) ? sInv : f;
    if (r == 0) pivb[l] = piv;
    #pragma unroll
    for (int j = 0; j < 32; ++j) row[j] -= f * prow[j];
    __syncthreads();
  }
}

// Trailing update: replay the 32 elementary ops on a 32-col tile held in registers.
__global__ __launch_bounds__(256) void k_trailF(float* __restrict__ W0,
                                                const float* __restrict__ Fg,
                                                const int* __restrict__ pivg, int kpanel){
  int s = blockIdx.y;
  float* buf = W0 + (size_t)s*131072;
  const float* Fb = Fg + (size_t)s*8192;
  const int* pivb = pivg + s*32;
  int r = threadIdx.x;
  int col0 = 32*(kpanel+1) + blockIdx.x*32;
  float row[32];
  #pragma unroll
  for (int j = 0; j < 32; j += 4){
    float4 v = *(const float4*)&buf[(size_t)r*512 + col0 + j];
    row[j] = v.x; row[j+1] = v.y; row[j+2] = v.z; row[j+3] = v.w;
  }
  __shared__ float Fl[32*256];
  __shared__ float xA[32], xB[32], prow[32];
  __shared__ int pvs[32];
  #pragma unroll
  for (int i = 0; i < 32; ++i) Fl[i*256 + r] = Fb[i*256 + r];
  if (r < 32) pvs[r] = pivb[r];
  __syncthreads();
  int c0 = kpanel*32;
  for (int l = 0; l < 32; ++l){
    int p = c0 + l;
    int piv = pvs[l];
    if (piv != p){
      if (r == p){
        #pragma unroll
        for (int j = 0; j < 32; ++j) xA[j] = row[j];
      }
      if (r == piv){
        #pragma unroll
        for (int j = 0; j < 32; ++j) xB[j] = row[j];
      }
      __syncthreads();
      if (r == p){
        #pragma unroll
        for (int j = 0; j < 32; ++j) row[j] = xB[j];
      }
      if (r == piv){
        #pragma unroll
        for (int j = 0; j < 32; ++j) row[j] = xA[j];
      }
    }
    float fv = Fl[l*256 + r];
    if (r == p){
      #pragma unroll
      for (int j = 0; j < 32; ++j){ row[j] *= fv; prow[j] = row[j]; }
    }
    __syncthreads();
    if (r != p){
      #pragma unroll
      for (int j = 0; j < 32; ++j) row[j] -= fv * prow[j];
    }
    __syncthreads();
  }
  #pragma unroll
  for (int j = 0; j < 32; j += 4){
    float4 v = make_float4(row[j], row[j+1], row[j+2], row[j+3]);
    *(float4*)&buf[(size_t)r*512 + col0 + j] = v;
  }
}

__global__ void k_y0(const float* __restrict__ W, double* __restrict__ Y){
  int s = blockIdx.y, i = blockIdx.x, j = threadIdx.x;
  Y[((size_t)s*256 + i)*256 + j] = (double)W[((size_t)s*256 + i)*512 + 256 + j];
}

// Z = M @ Y  (f64)
__global__ void k_mmZ(const double* __restrict__ M, const double* __restrict__ Y,
                      double* __restrict__ Z){
  int s = blockIdx.y;
  const double* A = M + (size_t)s*65536;
  const double* B = Y + (size_t)s*65536;
  int c = threadIdx.x, r0 = blockIdx.x * 8;
  double acc[8] = {0,0,0,0,0,0,0,0};
  for (int j = 0; j < 256; ++j){
    double b = B[(size_t)j*256 + c];
    #pragma unroll
    for (int q = 0; q < 8; ++q) acc[q] += A[(size_t)(r0+q)*256 + j] * b;
  }
  #pragma unroll
  for (int q = 0; q < 8; ++q) Z[(size_t)s*65536 + (size_t)(r0+q)*256 + c] = acc[q];
}

// Yn = 2Y - Y @ Z  (Newton-Schulz step, f64)
__global__ void k_mmN(const double* __restrict__ Y, const double* __restrict__ Z,
                      double* __restrict__ Yn){
  int s = blockIdx.y;
  const double* A = Y + (size_t)s*65536;
  const double* B = Z + (size_t)s*65536;
  int c = threadIdx.x, r0 = blockIdx.x * 8;
  double acc[8] = {0,0,0,0,0,0,0,0};
  for (int j = 0; j < 256; ++j){
    double b = B[(size_t)j*256 + c];
    #pragma unroll
    for (int q = 0; q < 8; ++q) acc[q] += A[(size_t)(r0+q)*256 + j] * b;
  }
  #pragma unroll
  for (int q = 0; q < 8; ++q)
    Yn[(size_t)s*65536 + (size_t)(r0+q)*256 + c] =
      2.0 * A[(size_t)(r0+q)*256 + c] - acc[q];
}

// Ad = 2*Minv - I (f32, into AP0); Bd = Minv @ (dt*B); V row0 = Bd
__global__ void k_final(const double* __restrict__ Y, float* __restrict__ Ad,
                        float* __restrict__ Bd, float* __restrict__ V){
  int s = blockIdx.y;
  const double* Ys = Y + (size_t)s*65536;
  if (blockIdx.x < 64){
    int c = threadIdx.x, r0 = blockIdx.x * 4;
    #pragma unroll
    for (int q = 0; q < 4; ++q){
      double v = 2.0 * Ys[(size_t)(r0+q)*256 + c] - ((r0+q) == c ? 1.0 : 0.0);
      Ad[(size_t)s*65536 + (size_t)(r0+q)*256 + c] = (float)v;
    }
  } else {
    int i = threadIdx.x;
    double dt = (1.0 / 192.0) / (double)(1 << s);
    double acc = 0.0;
    for (int j = 0; j < 256; ++j){
      double bj = dt * ((j & 1) ? -1.0 : 1.0) * (double)(2*j + 1);
      acc += Ys[(size_t)i*256 + j] * bj;
    }
    float b = (float)acc;
    Bd[s*256 + i] = b;
    V[((size_t)s*768 + 0)*256 + i] = b;
  }
}

// Legendre eval matrix (last 192 rows), f64 recurrence
__global__ void k_em(float* __restrict__ em){
  int s = blockIdx.x, t = threadIdx.x;
  int T = 192 << s;
  double dt = (1.0 / 192.0) / (double)(1 << s);
  double x = 1.0 - 2.0 * ((double)(T - 192 + t) * dt);
  float* row = em + ((size_t)s*192 + t)*256;
  double p0 = 1.0, p1 = x;
  row[0] = 1.0f; row[1] = (float)x;
  for (int n = 1; n < 255; ++n){
    double p2 = ((double)(2*n+1) * x * p1 - (double)n * p0) / (double)(n+1);
    row[n+1] = (float)p2;
    p0 = p1; p1 = p2;
  }
}

// one doubling level: Pout = Pin@Pin (bx<64); V[L..2L) = Pin @ V[0..L)  (bx>=64)
__global__ void k_level(const float* __restrict__ Pin, float* __restrict__ Pout,
                        float* __restrict__ V, int L){
  int s = blockIdx.y;
  const float* A = Pin + (size_t)s*65536;
  int bx = blockIdx.x;
  if (bx < 64){
    int c = threadIdx.x, r0 = bx * 4;
    float acc[4] = {0,0,0,0};
    for (int k = 0; k < 256; ++k){
      float b = A[(size_t)k*256 + c];
      #pragma unroll
      for (int q = 0; q < 4; ++q) acc[q] += A[(size_t)(r0+q)*256 + k] * b;
    }
    #pragma unroll
    for (int q = 0; q < 4; ++q) Pout[(size_t)s*65536 + (size_t)(r0+q)*256 + c] = acc[q];
  } else {
    int j = threadIdx.x;
    if (j >= L) return;
    int r0 = (bx - 64) * 4;
    float* Vs = V + (size_t)s*768*256;
    float acc[4] = {0,0,0,0};
    for (int k = 0; k < 256; ++k){
      float v = Vs[(size_t)j*256 + k];
      #pragma unroll
      for (int q = 0; q < 4; ++q) acc[q] += A[(size_t)(r0+q)*256 + k] * v;
    }
    #pragma unroll
    for (int q = 0; q < 4; ++q) Vs[(size_t)(L+j)*256 + r0 + q] = acc[q];
  }
}

// V[128*jc + r] = A128 @ V[128*(jc-1) + r]
__global__ void k_chunk(const float* __restrict__ A128, float* __restrict__ V, int jc){
  int s = blockIdx.y;
  const float* A = A128 + (size_t)s*65536;
  float* Vs = V + (size_t)s*768*256;
  int r = threadIdx.x;          // 0..127
  int r0 = blockIdx.x * 4;
  const float* vin = Vs + (size_t)(128*(jc-1) + r)*256;
  float acc[4] = {0,0,0,0};
  for (int k = 0; k < 256; ++k){
    float v = vin[k];
    #pragma unroll
    for (int q = 0; q < 4; ++q) acc[q] += A[(size_t)(r0+q)*256 + k] * v;
  }
  #pragma unroll
  for (int q = 0; q < 4; ++q) Vs[(size_t)(128*jc + r)*256 + r0 + q] = acc[q];
}

// Wt[s][i][col] with col = (kl*2+ri)*256 + o,  k = c8+kl
__global__ void k_wt(const float* __restrict__ wr, const float* __restrict__ wi,
                     float* __restrict__ Wt, int c8){
  int s = blockIdx.x, i = blockIdx.y, tid = threadIdx.x;
  size_t srcbase = ((size_t)s*256 + i)*256;
  float* dst = Wt + ((size_t)s*256 + i)*4096;
  for (int ph = 0; ph < 16; ++ph){
    int col = ph*256 + tid;
    int kl = col >> 9, ri = (col >> 8) & 1, o = col & 255;
    const float* src = ri ? wi : wr;
    dst[col] = src[(srcbase + o)*32 + c8 + kl];
  }
}

// U = V @ Wt   (M in {192,384,768}, N=4096, K=256), 64x64 tiles, 4x4 per thread
__global__ __launch_bounds__(256) void k_ugemm(const float* __restrict__ V,
                                               const float* __restrict__ Wt,
                                               float* __restrict__ U){
  int s = blockIdx.z;
  int Ts = 192 << s;
  int mt = blockIdx.y;
  if (mt*64 >= Ts) return;
  int nt = blockIdx.x;
  __shared__ float As[16][68];
  __shared__ float Bs[16][68];
  const float* Vs = V + (size_t)s*768*256;
  const float* Bm = Wt + (size_t)s*256*4096;
  int tid = threadIdx.x;
  int tm = tid >> 4, tn = tid & 15;
  float acc[4][4];
  #pragma unroll
  for (int a = 0; a < 4; ++a)
    #pragma unroll
    for (int b = 0; b < 4; ++b) acc[a][b] = 0.0f;
  int arow = mt*64 + (tid >> 2);
  int acol4 = (tid & 3) * 4;
  int brow = tid >> 4;
  int bcol = nt*64 + (tid & 15)*4;
  for (int k0 = 0; k0 < 256; k0 += 16){
    float4 a4 = *(const float4*)&Vs[(size_t)arow*256 + k0 + acol4];
    float4 b4 = *(const float4*)&Bm[(size_t)(k0 + brow)*4096 + bcol];
    As[acol4+0][tid>>2] = a4.x; As[acol4+1][tid>>2] = a4.y;
    As[acol4+2][tid>>2] = a4.z; As[acol4+3][tid>>2] = a4.w;
    *(float4*)&Bs[brow][(tid & 15)*4] = b4;
    __syncthreads();
    #pragma unroll
    for (int k = 0; k < 16; ++k){
      float av[4], bv[4];
      *(float4*)av = *(const float4*)&As[k][tm*4];
      *(float4*)bv = *(const float4*)&Bs[k][tn*4];
      #pragma unroll
      for (int a = 0; a < 4; ++a)
        #pragma unroll
        for (int b = 0; b < 4; ++b) acc[a][b] += av[a]*bv[b];
    }
    __syncthreads();
  }
  int ub = (s == 0) ? 0 : (s == 1 ? 192 : 576);
  size_t out0 = ((size_t)(ub + mt*64 + tm*4))*4096 + nt*64 + tn*4;
  #pragma unroll
  for (int a = 0; a < 4; ++a){
    float4 o4 = make_float4(acc[a][0], acc[a][1], acc[a][2], acc[a][3]);
    *(float4*)&U[out0 + (size_t)a*4096] = o4;
  }
}

// ---- two-phase parallel scan ----
__global__ void k_scanA(float* __restrict__ U, float* __restrict__ Seg, int c8){
  int seg = blockIdx.x;      // 0..7
  int kl  = blockIdx.y;      // 0..7
  int s   = blockIdx.z;      // 0..2
  int k = c8 + kl;
  int T = 192 << s;
  int Ls = T >> 3;
  int m0 = seg * Ls;
  int ub = (s == 0) ? 0 : (s == 1 ? 192 : 576);
  int o = threadIdx.x;
  float* Ur = U + ((size_t)(ub + m0))*4096 + kl*512 + o;
  float th = 6.283185307179586f / (float)T;
  int im = (k * m0) % T;
  float Zr = 0.f, Zi = 0.f;
  #pragma unroll 4
  for (int i = 0; i < Ls; ++i){
    float ur = Ur[0];
    float ui = Ur[256];
    float sa, ca; __sincosf(th * (float)im, &sa, &ca);
    Zr += ca*ur + sa*ui;
    Zi += ca*ui - sa*ur;
    Ur[0] = Zr; Ur[256] = Zi;
    im += k; if (im >= T) im -= T;
    Ur += 4096;
  }
  float* Sg = Seg + (((size_t)(s*8 + kl)*8 + seg)*2)*256 + o;
  Sg[0] = Zr; Sg[256] = Zi;
}

__global__ void k_scanC(const float* __restrict__ U, const float* __restrict__ Seg,
                        float* __restrict__ C8, int c8){
  int seg = blockIdx.x, kl = blockIdx.y, s = blockIdx.z;
  int k = c8 + kl;
  int T = 192 << s;
  int Ls = T >> 3;
  int m0 = seg * Ls;
  int ub = (s == 0) ? 0 : (s == 1 ? 192 : 576);
  int o = threadIdx.x;
  float offr = 0.f, offi = 0.f;
  const float* Sg = Seg + ((size_t)(s*8 + kl)*8)*512 + o;
  for (int j = 0; j < seg; ++j){ offr += Sg[(size_t)j*512]; offi += Sg[(size_t)j*512 + 256]; }
  const float* Ur = U + ((size_t)(ub + m0))*4096 + kl*512 + o;
  float* Cb = C8 + ((size_t)kl*1344 + ub)*256 + o;
  float ckT = ((k == 0) ? 1.0f : 2.0f) / (float)T;
  float th = 6.283185307179586f / (float)T;
  int ib = (k * (192 + m0)) % T;
  #pragma unroll 4
  for (int i = 0; i < Ls; ++i){
    int m = m0 + i;
    float zr = offr + Ur[0];
    float zi = offi + Ur[256];
    float sb, cb; __sincosf(th * (float)ib, &sb, &cb);
    Cb[(size_t)(T-1-m)*256] = ckT * (zr*cb - zi*sb);
    ib += k; if (ib >= T) ib -= T;
    Ur += 4096;
  }
}

// P[row][o] (+)= sum_kl C8[kl][row][o]
__global__ void k_reduce(const float* __restrict__ C8, float* __restrict__ P, int first){
  int row = blockIdx.x;    // 0..1343
  int o = threadIdx.x;
  float a = 0.f;
  #pragma unroll
  for (int kl = 0; kl < 8; ++kl) a += C8[((size_t)kl*1344 + row)*256 + o];
  size_t idx = (size_t)row*256 + o;
  if (first) P[idx] = a; else P[idx] += a;
}

// K[to][tg] = sum_s mlpw[s] * sum_o em[s][to][o] * P[s][tg-off][o]
__global__ void k_K(const float* __restrict__ em, const float* __restrict__ P,
                    const float* __restrict__ mlpw, float* __restrict__ K){
  int to = blockIdx.y;
  int tg = blockIdx.x*64 + threadIdx.x;
  float acc = 0.f;
  for (int s = 0; s < 3; ++s){
    int T = 192 << s;
    int off = 768 - T;
    if (tg >= off){
      int ub = (s == 0) ? 0 : (s == 1 ? 192 : 576);
      const float* Pr = P + ((size_t)ub + (tg - off))*256;
      const float* er = em + ((size_t)s*192 + to)*256;
      float a = 0.f;
      for (int o2 = 0; o2 < 256; ++o2) a += er[o2] * Pr[o2];
      acc += mlpw[s] * a;
    }
  }
  K[(size_t)to*768 + tg] = acc;
}

// out[b][to][d] = mlp_b + sum_t K[to][t] * inputs[b][t][d]
__global__ void k_out(const float* __restrict__ K, const float* __restrict__ inp,
                      const float* __restrict__ mlpb, float* __restrict__ out){
  int to = blockIdx.x, b = blockIdx.y, d = threadIdx.x;
  const float* Kr = K + (size_t)to*768;
  const float* ip = inp + (size_t)b*768*64 + d;
  float acc = mlpb[0];
  #pragma unroll 4
  for (int t = 0; t < 768; ++t) acc += Kr[t] * ip[(size_t)t*64];
  out[((size_t)b*192 + to)*64 + d] = acc;
}

extern "C" void kernel_launch(void* const* d_in, const int* in_sizes, int n_in,
                              void* d_out, int out_size, void* d_ws, size_t ws_size,
                              hipStream_t stream){
  const float* inputs  = (const float*)d_in[0];
  const float* spec_wr = (const float*)d_in[1];
  const float* spec_wi = (const float*)d_in[2];
  const float* mlp_w   = (const float*)d_in[3];
  const float* mlp_b   = (const float*)d_in[4];
  float* out = (float*)d_out;
  char* ws = (char*)d_ws;

  double* Mf64 = (double*)(ws + OFF_MF64);
  double* Ya   = (double*)(ws + OFF_YA);
  double* Yb   = (double*)(ws + OFF_YB);
  double* Zb   = (double*)(ws + OFF_Z);
  float* W0  = (float*)(ws + OFF_W0);
  float* Fg  = (float*)(ws + OFF_F);
  int*   pivg= (int*)(ws + OFF_PIV);
  float* AP0 = (float*)(ws + OFF_AP0);
  float* AP1 = (float*)(ws + OFF_AP1);
  float* Bd  = (float*)(ws + OFF_BD);
  float* V   = (float*)(ws + OFF_V);
  float* em  = (float*)(ws + OFF_EM);
  float* P   = (float*)(ws + OFF_P);
  float* Km  = (float*)(ws + OFF_K);
  float* Wt  = (float*)(ws + OFF_WT);
  float* U   = (float*)(ws + OFF_U);
  float* C8  = (float*)(ws + OFF_C8);
  float* Seg = (float*)(ws + OFF_SEG);

  k_init<<<dim3(256,3), 256, 0, stream>>>(Mf64, W0);

  for (int kp = 0; kp < 8; ++kp){
    k_panelF<<<3, 256, 0, stream>>>(W0, Fg, pivg, kp);
    k_trailF<<<dim3(15-kp,3), 256, 0, stream>>>(W0, Fg, pivg, kp);
  }
  // Minv (f32) now in W0 right half
  k_y0<<<dim3(256,3), 256, 0, stream>>>(W0, Ya);
  for (int it = 0; it < 3; ++it){
    double* yi = (it & 1) ? Yb : Ya;
    double* yo = (it & 1) ? Ya : Yb;
    k_mmZ<<<dim3(32,3), 256, 0, stream>>>(Mf64, yi, Zb);
    k_mmN<<<dim3(32,3), 256, 0, stream>>>(yi, Zb, yo);
  }
  // refined Minv in Yb (3 Newton iters: Ya->Yb->Ya->Yb)
  k_final<<<dim3(65,3), 256, 0, stream>>>(Yb, AP0, Bd, V);
  k_em<<<3, 192, 0, stream>>>(em);

  float* pin = AP0; float* pout = AP1;
  for (int L = 1; L <= 64; L <<= 1){
    k_level<<<dim3(128,3), 256, 0, stream>>>(pin, pout, V, L);
    float* t = pin; pin = pout; pout = t;
  }
  for (int jc = 1; jc <= 5; ++jc)
    k_chunk<<<dim3(64,3), 128, 0, stream>>>(pin, V, jc);

  for (int c = 0; c < 4; ++c){
    k_wt<<<dim3(3,256), 256, 0, stream>>>(spec_wr, spec_wi, Wt, c*8);
    k_ugemm<<<dim3(64,12,3), 256, 0, stream>>>(V, Wt, U);
    k_scanA<<<dim3(8,8,3), 256, 0, stream>>>(U, Seg, c*8);
    k_scanC<<<dim3(8,8,3), 256, 0, stream>>>(U, Seg, C8, c*8);
    k_reduce<<<1344, 256, 0, stream>>>(C8, P, (c == 0) ? 1 : 0);
  }
  k_K<<<dim3(12,192), 64, 0, stream>>>(em, P, mlp_w, Km);
  k_out<<<dim3(192,8), 64, 0, stream>>>(Km, inputs, mlp_b, out);
}

// Round 5
// 1357.200 us; speedup vs baseline: 2.3460x; 1.0432x over previous
//
#include <hip/hip_runtime.h>

// FiLM forward == fixed linear map K (192x768) applied to inputs (8,768,64), K rebuilt
// on-device each call from spec weights + HiPPO-LegT constants.
// Inversion: pivoted Gauss-Jordan (numerically required: LegT A is severely non-normal;
// Neumann/NS-from-scratch overflows f32 -- round-3 lesson), register-row panel +
// factor-replay trailing update, then 2 batched f64 Newton polish iterations.
// Chunk-phase scratch C8/Seg alias the (dead by then) inversion/AP regions.

#define OFF_MF64  0
#define OFF_YA    1572864
#define OFF_YB    3145728
#define OFF_Z     4718592
#define OFF_W0    6291456     // [3][256][512] f32 augmented [M | I], in-place GJ
#define OFF_F     7864320     // [3][32][256] f32 per-panel elementary factors
#define OFF_PIV   7962624     // [3][32] int pivots
#define OFF_AP0   10223616
#define OFF_AP1   11010048
#define OFF_BD    11796480
#define OFF_V     11800576
#define OFF_EM    14159872
#define OFF_P     14749696
#define OFF_K     16125952
#define OFF_WT    16715776
#define OFF_U     29298688
// aliases (live only during chunk phase; inversion/AP regions dead by then)
#define OFF_C8    0
#define OFF_SEG   11010048

__device__ __forceinline__ double a_entry(int i, int j){
  double base = (i < j) ? -1.0 : (((i - j) & 1) ? 1.0 : -1.0);  // (-1)^(i-j+1) for i>=j
  return base * (double)(2*i + 1);
}

// Build Mf64 = I - dt/2*A  and GJ working buffer W0 = [M_f32 | I]
__global__ void k_init(double* __restrict__ Mf64, float* __restrict__ W0){
  int s = blockIdx.y, i = blockIdx.x, j = threadIdx.x;
  double dt = (1.0 / 192.0) / (double)(1 << s);
  double m = ((i == j) ? 1.0 : 0.0) - 0.5 * dt * a_entry(i, j);
  Mf64[((size_t)s*256 + i)*256 + j] = m;
  float* w = W0 + ((size_t)s*256 + i)*512;
  w[j] = (float)m;
  w[256 + j] = (i == j) ? 1.0f : 0.0f;
}

// Panel factorization: pivoted GJ on 32-col panel, one row per thread in registers.
__global__ __launch_bounds__(256) void k_panelF(float* __restrict__ W0,
                                                float* __restrict__ Fg,
                                                int* __restrict__ pivg, int kpanel){
  int s = blockIdx.x;
  float* buf = W0 + (size_t)s*131072;
  float* Fb = Fg + (size_t)s*8192;
  int* pivb = pivg + s*32;
  int r = threadIdx.x;
  int c0 = kpanel*32;
  float row[32];
  #pragma unroll
  for (int j = 0; j < 32; j += 4){
    float4 v = *(const float4*)&buf[(size_t)r*512 + c0 + j];
    row[j] = v.x; row[j+1] = v.y; row[j+2] = v.z; row[j+3] = v.w;
  }
  __shared__ float xA[32], xB[32], prow[32], wv[4], sInv;
  __shared__ int wi[4];
  #pragma unroll
  for (int l = 0; l < 32; ++l){
    int p = c0 + l;
    float a = (r >= p) ? fabsf(row[l]) : -1.0f;
    int bi = r;
    #pragma unroll
    for (int off = 32; off > 0; off >>= 1){
      float oa = __shfl_xor(a, off);
      int ob = __shfl_xor(bi, off);
      if (oa > a || (oa == a && ob < bi)){ a = oa; bi = ob; }
    }
    if ((r & 63) == 0){ wv[r >> 6] = a; wi[r >> 6] = bi; }
    __syncthreads();
    float best = wv[0]; int piv = wi[0];
    #pragma unroll
    for (int w = 1; w < 4; ++w){
      if (wv[w] > best || (wv[w] == best && wi[w] < piv)){ best = wv[w]; piv = wi[w]; }
    }
    if (piv != p){
      if (r == p){
        #pragma unroll
        for (int j = 0; j < 32; ++j) xA[j] = row[j];
      }
      if (r == piv){
        #pragma unroll
        for (int j = 0; j < 32; ++j) xB[j] = row[j];
      }
      __syncthreads();
      if (r == p){
        #pragma unroll
        for (int j = 0; j < 32; ++j) row[j] = xB[j];
      }
      if (r == piv){
        #pragma unroll
        for (int j = 0; j < 32; ++j) row[j] = xA[j];
      }
    }
    if (r == p){
      float inv = 1.0f / row[l];
      sInv = inv;
      #pragma unroll
      for (int j = 0; j < 32; ++j){ row[j] *= inv; prow[j] = row[j]; }
    }
    __syncthreads();
    float f = (r == p) ? 0.0f : row[l];
    Fb[l*256 + r] = (r == p) ? sInv : f;
    if (r == 0) pivb[l] = piv;
    #pragma unroll
    for (int j = 0; j < 32; ++j) row[j] -= f * prow[j];
    __syncthreads();
  }
}

// Trailing update: replay the 32 elementary ops on a 32-col tile held in registers.
__global__ __launch_bounds__(256) void k_trailF(float* __restrict__ W0,
                                                const float* __restrict__ Fg,
                                                const int* __restrict__ pivg, int kpanel){
  int s = blockIdx.y;
  float* buf = W0 + (size_t)s*131072;
  const float* Fb = Fg + (size_t)s*8192;
  const int* pivb = pivg + s*32;
  int r = threadIdx.x;
  int col0 = 32*(kpanel+1) + blockIdx.x*32;
  float row[32];
  #pragma unroll
  for (int j = 0; j < 32; j += 4){
    float4 v = *(const float4*)&buf[(size_t)r*512 + col0 + j];
    row[j] = v.x; row[j+1] = v.y; row[j+2] = v.z; row[j+3] = v.w;
  }
  __shared__ float Fl[32*256];
  __shared__ float xA[32], xB[32], prow[32];
  __shared__ int pvs[32];
  #pragma unroll
  for (int i = 0; i < 32; ++i) Fl[i*256 + r] = Fb[i*256 + r];
  if (r < 32) pvs[r] = pivb[r];
  __syncthreads();
  int c0 = kpanel*32;
  for (int l = 0; l < 32; ++l){
    int p = c0 + l;
    int piv = pvs[l];
    if (piv != p){
      if (r == p){
        #pragma unroll
        for (int j = 0; j < 32; ++j) xA[j] = row[j];
      }
      if (r == piv){
        #pragma unroll
        for (int j = 0; j < 32; ++j) xB[j] = row[j];
      }
      __syncthreads();
      if (r == p){
        #pragma unroll
        for (int j = 0; j < 32; ++j) row[j] = xB[j];
      }
      if (r == piv){
        #pragma unroll
        for (int j = 0; j < 32; ++j) row[j] = xA[j];
      }
    }
    float fv = Fl[l*256 + r];
    if (r == p){
      #pragma unroll
      for (int j = 0; j < 32; ++j){ row[j] *= fv; prow[j] = row[j]; }
    }
    __syncthreads();
    if (r != p){
      #pragma unroll
      for (int j = 0; j < 32; ++j) row[j] -= fv * prow[j];
    }
    __syncthreads();
  }
  #pragma unroll
  for (int j = 0; j < 32; j += 4){
    float4 v = make_float4(row[j], row[j+1], row[j+2], row[j+3]);
    *(float4*)&buf[(size_t)r*512 + col0 + j] = v;
  }
}

__global__ void k_y0(const float* __restrict__ W, double* __restrict__ Y){
  int s = blockIdx.y, i = blockIdx.x, j = threadIdx.x;
  Y[((size_t)s*256 + i)*256 + j] = (double)W[((size_t)s*256 + i)*512 + 256 + j];
}

// Z = M @ Y  (f64)
__global__ void k_mmZ(const double* __restrict__ M, const double* __restrict__ Y,
                      double* __restrict__ Z){
  int s = blockIdx.y;
  const double* A = M + (size_t)s*65536;
  const double* B = Y + (size_t)s*65536;
  int c = threadIdx.x, r0 = blockIdx.x * 8;
  double acc[8] = {0,0,0,0,0,0,0,0};
  for (int j = 0; j < 256; ++j){
    double b = B[(size_t)j*256 + c];
    #pragma unroll
    for (int q = 0; q < 8; ++q) acc[q] += A[(size_t)(r0+q)*256 + j] * b;
  }
  #pragma unroll
  for (int q = 0; q < 8; ++q) Z[(size_t)s*65536 + (size_t)(r0+q)*256 + c] = acc[q];
}

// Yn = 2Y - Y @ Z  (Newton-Schulz step, f64)
__global__ void k_mmN(const double* __restrict__ Y, const double* __restrict__ Z,
                      double* __restrict__ Yn){
  int s = blockIdx.y;
  const double* A = Y + (size_t)s*65536;
  const double* B = Z + (size_t)s*65536;
  int c = threadIdx.x, r0 = blockIdx.x * 8;
  double acc[8] = {0,0,0,0,0,0,0,0};
  for (int j = 0; j < 256; ++j){
    double b = B[(size_t)j*256 + c];
    #pragma unroll
    for (int q = 0; q < 8; ++q) acc[q] += A[(size_t)(r0+q)*256 + j] * b;
  }
  #pragma unroll
  for (int q = 0; q < 8; ++q)
    Yn[(size_t)s*65536 + (size_t)(r0+q)*256 + c] =
      2.0 * A[(size_t)(r0+q)*256 + c] - acc[q];
}

// Ad = 2*Minv - I (f32, into AP0); Bd = Minv @ (dt*B); V row0 = Bd
__global__ void k_final(const double* __restrict__ Y, float* __restrict__ Ad,
                        float* __restrict__ Bd, float* __restrict__ V){
  int s = blockIdx.y;
  const double* Ys = Y + (size_t)s*65536;
  if (blockIdx.x < 64){
    int c = threadIdx.x, r0 = blockIdx.x * 4;
    #pragma unroll
    for (int q = 0; q < 4; ++q){
      double v = 2.0 * Ys[(size_t)(r0+q)*256 + c] - ((r0+q) == c ? 1.0 : 0.0);
      Ad[(size_t)s*65536 + (size_t)(r0+q)*256 + c] = (float)v;
    }
  } else {
    int i = threadIdx.x;
    double dt = (1.0 / 192.0) / (double)(1 << s);
    double acc = 0.0;
    for (int j = 0; j < 256; ++j){
      double bj = dt * ((j & 1) ? -1.0 : 1.0) * (double)(2*j + 1);
      acc += Ys[(size_t)i*256 + j] * bj;
    }
    float b = (float)acc;
    Bd[s*256 + i] = b;
    V[((size_t)s*768 + 0)*256 + i] = b;
  }
}

// Legendre eval matrix (last 192 rows), f64 recurrence
__global__ void k_em(float* __restrict__ em){
  int s = blockIdx.x, t = threadIdx.x;
  int T = 192 << s;
  double dt = (1.0 / 192.0) / (double)(1 << s);
  double x = 1.0 - 2.0 * ((double)(T - 192 + t) * dt);
  float* row = em + ((size_t)s*192 + t)*256;
  double p0 = 1.0, p1 = x;
  row[0] = 1.0f; row[1] = (float)x;
  for (int n = 1; n < 255; ++n){
    double p2 = ((double)(2*n+1) * x * p1 - (double)n * p0) / (double)(n+1);
    row[n+1] = (float)p2;
    p0 = p1; p1 = p2;
  }
}

// one doubling level: Pout = Pin@Pin (bx<64); V[L..2L) = Pin @ V[0..L)  (bx>=64)
__global__ void k_level(const float* __restrict__ Pin, float* __restrict__ Pout,
                        float* __restrict__ V, int L){
  int s = blockIdx.y;
  const float* A = Pin + (size_t)s*65536;
  int bx = blockIdx.x;
  if (bx < 64){
    int c = threadIdx.x, r0 = bx * 4;
    float acc[4] = {0,0,0,0};
    for (int k = 0; k < 256; ++k){
      float b = A[(size_t)k*256 + c];
      #pragma unroll
      for (int q = 0; q < 4; ++q) acc[q] += A[(size_t)(r0+q)*256 + k] * b;
    }
    #pragma unroll
    for (int q = 0; q < 4; ++q) Pout[(size_t)s*65536 + (size_t)(r0+q)*256 + c] = acc[q];
  } else {
    int j = threadIdx.x;
    if (j >= L) return;
    int r0 = (bx - 64) * 4;
    float* Vs = V + (size_t)s*768*256;
    float acc[4] = {0,0,0,0};
    for (int k = 0; k < 256; ++k){
      float v = Vs[(size_t)j*256 + k];
      #pragma unroll
      for (int q = 0; q < 4; ++q) acc[q] += A[(size_t)(r0+q)*256 + k] * v;
    }
    #pragma unroll
    for (int q = 0; q < 4; ++q) Vs[(size_t)(L+j)*256 + r0 + q] = acc[q];
  }
}

// V[128*jc + r] = A128 @ V[128*(jc-1) + r]
__global__ void k_chunk(const float* __restrict__ A128, float* __restrict__ V, int jc){
  int s = blockIdx.y;
  const float* A = A128 + (size_t)s*65536;
  float* Vs = V + (size_t)s*768*256;
  int r = threadIdx.x;          // 0..127
  int r0 = blockIdx.x * 4;
  const float* vin = Vs + (size_t)(128*(jc-1) + r)*256;
  float acc[4] = {0,0,0,0};
  for (int k = 0; k < 256; ++k){
    float v = vin[k];
    #pragma unroll
    for (int q = 0; q < 4; ++q) acc[q] += A[(size_t)(r0+q)*256 + k] * v;
  }
  #pragma unroll
  for (int q = 0; q < 4; ++q) Vs[(size_t)(128*jc + r)*256 + r0 + q] = acc[q];
}

// Wt[s][i][col] with col = (kl*2+ri)*256 + o,  k = c8+kl
__global__ void k_wt(const float* __restrict__ wr, const float* __restrict__ wi,
                     float* __restrict__ Wt, int c8){
  int s = blockIdx.x, i = blockIdx.y, tid = threadIdx.x;
  size_t srcbase = ((size_t)s*256 + i)*256;
  float* dst = Wt + ((size_t)s*256 + i)*4096;
  for (int ph = 0; ph < 16; ++ph){
    int col = ph*256 + tid;
    int kl = col >> 9, ri = (col >> 8) & 1, o = col & 255;
    const float* src = ri ? wi : wr;
    dst[col] = src[(srcbase + o)*32 + c8 + kl];
  }
}

// U = V @ Wt   (M in {192,384,768}, N=4096, K=256)
// 64x128 tile, 256 threads, 4x(4+4) accum per thread; B read as two stride-4 groups
// (2-way LDS aliasing only -> free on gfx950).
__global__ __launch_bounds__(256) void k_ugemm(const float* __restrict__ V,
                                               const float* __restrict__ Wt,
                                               float* __restrict__ U){
  int s = blockIdx.z;
  int Ts = 192 << s;
  int mt = blockIdx.y;
  if (mt*64 >= Ts) return;
  int nt = blockIdx.x;           // 0..31, 128 cols each
  __shared__ float As[16][68];
  __shared__ float Bs[16][132];
  const float* Vs = V + (size_t)s*768*256;
  const float* Bm = Wt + (size_t)s*256*4096;
  int tid = threadIdx.x;
  int tm = tid >> 4, tn = tid & 15;
  float acc[4][8];
  #pragma unroll
  for (int a = 0; a < 4; ++a)
    #pragma unroll
    for (int b = 0; b < 8; ++b) acc[a][b] = 0.0f;
  int arow = mt*64 + (tid >> 2);
  int acol4 = (tid & 3) * 4;
  for (int k0 = 0; k0 < 256; k0 += 16){
    float4 a4 = *(const float4*)&Vs[(size_t)arow*256 + k0 + acol4];
    As[acol4+0][tid>>2] = a4.x; As[acol4+1][tid>>2] = a4.y;
    As[acol4+2][tid>>2] = a4.z; As[acol4+3][tid>>2] = a4.w;
    #pragma unroll
    for (int h = 0; h < 2; ++h){
      int p = tid + h*256;
      int br = p >> 5, bc = (p & 31) * 4;
      float4 b4 = *(const float4*)&Bm[(size_t)(k0 + br)*4096 + nt*128 + bc];
      *(float4*)&Bs[br][bc] = b4;
    }
    __syncthreads();
    #pragma unroll
    for (int k = 0; k < 16; ++k){
      float av[4], bv[8];
      *(float4*)av = *(const float4*)&As[k][tm*4];
      *(float4*)&bv[0] = *(const float4*)&Bs[k][tn*4];
      *(float4*)&bv[4] = *(const float4*)&Bs[k][64 + tn*4];
      #pragma unroll
      for (int a = 0; a < 4; ++a)
        #pragma unroll
        for (int b = 0; b < 8; ++b) acc[a][b] += av[a]*bv[b];
    }
    __syncthreads();
  }
  int ub = (s == 0) ? 0 : (s == 1 ? 192 : 576);
  size_t rbase = ((size_t)(ub + mt*64 + tm*4))*4096 + nt*128;
  #pragma unroll
  for (int a = 0; a < 4; ++a){
    float4 o0 = make_float4(acc[a][0], acc[a][1], acc[a][2], acc[a][3]);
    float4 o1 = make_float4(acc[a][4], acc[a][5], acc[a][6], acc[a][7]);
    *(float4*)&U[rbase + (size_t)a*4096 + tn*4] = o0;
    *(float4*)&U[rbase + (size_t)a*4096 + 64 + tn*4] = o1;
  }
}

// ---- two-phase parallel scan ----
__global__ void k_scanA(float* __restrict__ U, float* __restrict__ Seg, int c8){
  int seg = blockIdx.x;      // 0..7
  int kl  = blockIdx.y;      // 0..7
  int s   = blockIdx.z;      // 0..2
  int k = c8 + kl;
  int T = 192 << s;
  int Ls = T >> 3;
  int m0 = seg * Ls;
  int ub = (s == 0) ? 0 : (s == 1 ? 192 : 576);
  int o = threadIdx.x;
  float* Ur = U + ((size_t)(ub + m0))*4096 + kl*512 + o;
  float th = 6.283185307179586f / (float)T;
  int im = (k * m0) % T;
  float Zr = 0.f, Zi = 0.f;
  #pragma unroll 4
  for (int i = 0; i < Ls; ++i){
    float ur = Ur[0];
    float ui = Ur[256];
    float sa, ca; __sincosf(th * (float)im, &sa, &ca);
    Zr += ca*ur + sa*ui;
    Zi += ca*ui - sa*ur;
    Ur[0] = Zr; Ur[256] = Zi;
    im += k; if (im >= T) im -= T;
    Ur += 4096;
  }
  float* Sg = Seg + (((size_t)(s*8 + kl)*8 + seg)*2)*256 + o;
  Sg[0] = Zr; Sg[256] = Zi;
}

__global__ void k_scanC(const float* __restrict__ U, const float* __restrict__ Seg,
                        float* __restrict__ C8, int c8){
  int seg = blockIdx.x, kl = blockIdx.y, s = blockIdx.z;
  int k = c8 + kl;
  int T = 192 << s;
  int Ls = T >> 3;
  int m0 = seg * Ls;
  int ub = (s == 0) ? 0 : (s == 1 ? 192 : 576);
  int o = threadIdx.x;
  float offr = 0.f, offi = 0.f;
  const float* Sg = Seg + ((size_t)(s*8 + kl)*8)*512 + o;
  for (int j = 0; j < seg; ++j){ offr += Sg[(size_t)j*512]; offi += Sg[(size_t)j*512 + 256]; }
  const float* Ur = U + ((size_t)(ub + m0))*4096 + kl*512 + o;
  float* Cb = C8 + ((size_t)kl*1344 + ub)*256 + o;
  float ckT = ((k == 0) ? 1.0f : 2.0f) / (float)T;
  float th = 6.283185307179586f / (float)T;
  int ib = (k * (192 + m0)) % T;
  #pragma unroll 4
  for (int i = 0; i < Ls; ++i){
    int m = m0 + i;
    float zr = offr + Ur[0];
    float zi = offi + Ur[256];
    float sb, cb; __sincosf(th * (float)ib, &sb, &cb);
    Cb[(size_t)(T-1-m)*256] = ckT * (zr*cb - zi*sb);
    ib += k; if (ib >= T) ib -= T;
    Ur += 4096;
  }
}

// P[row][o] (+)= sum_kl C8[kl][row][o]
__global__ void k_reduce(const float* __restrict__ C8, float* __restrict__ P, int first){
  int row = blockIdx.x;    // 0..1343
  int o = threadIdx.x;
  float a = 0.f;
  #pragma unroll
  for (int kl = 0; kl < 8; ++kl) a += C8[((size_t)kl*1344 + row)*256 + o];
  size_t idx = (size_t)row*256 + o;
  if (first) P[idx] = a; else P[idx] += a;
}

// K[to][tg] = sum_s mlpw[s] * sum_o em[s][to][o] * P[s][tg-off][o]
// 4 waves split the o-dimension, LDS combine.
__global__ __launch_bounds__(256) void k_K(const float* __restrict__ em,
                                           const float* __restrict__ P,
                                           const float* __restrict__ mlpw,
                                           float* __restrict__ K){
  int to = blockIdx.y;
  int d = threadIdx.x & 63;
  int w = threadIdx.x >> 6;
  int tg = blockIdx.x*64 + d;
  float acc = 0.f;
  for (int s = 0; s < 3; ++s){
    int T = 192 << s;
    int off = 768 - T;
    if (tg >= off){
      int ub = (s == 0) ? 0 : (s == 1 ? 192 : 576);
      const float* Pr = P + ((size_t)ub + (tg - off))*256 + w*64;
      const float* er = em + ((size_t)s*192 + to)*256 + w*64;
      float a = 0.f;
      for (int o2 = 0; o2 < 64; ++o2) a += er[o2] * Pr[o2];
      acc += mlpw[s] * a;
    }
  }
  __shared__ float red[4][64];
  red[w][d] = acc;
  __syncthreads();
  if (w == 0)
    K[(size_t)to*768 + tg] = red[0][d] + red[1][d] + red[2][d] + red[3][d];
}

// out[b][to][d] = mlp_b + sum_t K[to][t] * inputs[b][t][d]
// 4 waves split the t-dimension, LDS combine.
__global__ __launch_bounds__(256) void k_out(const float* __restrict__ K,
                                             const float* __restrict__ inp,
                                             const float* __restrict__ mlpb,
                                             float* __restrict__ out){
  int to = blockIdx.x, b = blockIdx.y;
  int d = threadIdx.x & 63;
  int w = threadIdx.x >> 6;
  const float* Kr = K + (size_t)to*768 + w*192;
  const float* ip = inp + (size_t)b*768*64 + (size_t)(w*192)*64 + d;
  float acc = 0.f;
  #pragma unroll 4
  for (int i = 0; i < 192; ++i) acc += Kr[i] * ip[(size_t)i*64];
  __shared__ float red[4][64];
  red[w][d] = acc;
  __syncthreads();
  if (w == 0)
    out[((size_t)b*192 + to)*64 + d] =
      red[0][d] + red[1][d] + red[2][d] + red[3][d] + mlpb[0];
}

extern "C" void kernel_launch(void* const* d_in, const int* in_sizes, int n_in,
                              void* d_out, int out_size, void* d_ws, size_t ws_size,
                              hipStream_t stream){
  const float* inputs  = (const float*)d_in[0];
  const float* spec_wr = (const float*)d_in[1];
  const float* spec_wi = (const float*)d_in[2];
  const float* mlp_w   = (const float*)d_in[3];
  const float* mlp_b   = (const float*)d_in[4];
  float* out = (float*)d_out;
  char* ws = (char*)d_ws;

  double* Mf64 = (double*)(ws + OFF_MF64);
  double* Ya   = (double*)(ws + OFF_YA);
  double* Yb   = (double*)(ws + OFF_YB);
  double* Zb   = (double*)(ws + OFF_Z);
  float* W0  = (float*)(ws + OFF_W0);
  float* Fg  = (float*)(ws + OFF_F);
  int*   pivg= (int*)(ws + OFF_PIV);
  float* AP0 = (float*)(ws + OFF_AP0);
  float* AP1 = (float*)(ws + OFF_AP1);
  float* Bd  = (float*)(ws + OFF_BD);
  float* V   = (float*)(ws + OFF_V);
  float* em  = (float*)(ws + OFF_EM);
  float* P   = (float*)(ws + OFF_P);
  float* Km  = (float*)(ws + OFF_K);
  float* Wt  = (float*)(ws + OFF_WT);
  float* U   = (float*)(ws + OFF_U);
  float* C8  = (float*)(ws + OFF_C8);
  float* Seg = (float*)(ws + OFF_SEG);

  k_init<<<dim3(256,3), 256, 0, stream>>>(Mf64, W0);

  for (int kp = 0; kp < 8; ++kp){
    k_panelF<<<3, 256, 0, stream>>>(W0, Fg, pivg, kp);
    k_trailF<<<dim3(15-kp,3), 256, 0, stream>>>(W0, Fg, pivg, kp);
  }
  // Minv (f32) now in W0 right half
  k_y0<<<dim3(256,3), 256, 0, stream>>>(W0, Ya);
  for (int it = 0; it < 2; ++it){
    double* yi = (it & 1) ? Yb : Ya;
    double* yo = (it & 1) ? Ya : Yb;
    k_mmZ<<<dim3(32,3), 256, 0, stream>>>(Mf64, yi, Zb);
    k_mmN<<<dim3(32,3), 256, 0, stream>>>(yi, Zb, yo);
  }
  // refined Minv in Ya (2 Newton iters: Ya->Yb->Ya)
  k_final<<<dim3(65,3), 256, 0, stream>>>(Ya, AP0, Bd, V);
  k_em<<<3, 192, 0, stream>>>(em);

  float* pin = AP0; float* pout = AP1;
  for (int L = 1; L <= 64; L <<= 1){
    k_level<<<dim3(128,3), 256, 0, stream>>>(pin, pout, V, L);
    float* t = pin; pin = pout; pout = t;
  }
  for (int jc = 1; jc <= 5; ++jc)
    k_chunk<<<dim3(64,3), 128, 0, stream>>>(pin, V, jc);

  for (int c = 0; c < 4; ++c){
    k_wt<<<dim3(3,256), 256, 0, stream>>>(spec_wr, spec_wi, Wt, c*8);
    k_ugemm<<<dim3(32,12,3), 256, 0, stream>>>(V, Wt, U);
    k_scanA<<<dim3(8,8,3), 256, 0, stream>>>(U, Seg, c*8);
    k_scanC<<<dim3(8,8,3), 256, 0, stream>>>(U, Seg, C8, c*8);
    k_reduce<<<1344, 256, 0, stream>>>(C8, P, (c == 0) ? 1 : 0);
  }
  k_K<<<dim3(12,192), 256, 0, stream>>>(em, P, mlp_w, Km);
  k_out<<<dim3(192,8), 256, 0, stream>>>(Km, inputs, mlp_b, out);
}

// Round 6
// 1241.091 us; speedup vs baseline: 2.5655x; 1.0936x over previous
//
#include <hip/hip_runtime.h>

// FiLM forward == fixed linear map K (192x768) applied to inputs (8,768,64), K rebuilt
// on-device each call from spec weights + HiPPO-LegT constants.
// Inversion: pivoted Gauss-Jordan (numerically required: LegT A is severely non-normal;
// Neumann/NS-from-scratch overflows f32 -- round-3 lesson), register-row panel +
// factor-replay trailing update, then 2 batched f64 Newton polish iterations.
// U-GEMM: fp16 2-way-split MFMA (16x16x32_f16, 3 terms hh/hl/lh; exact 2^k scaling
// V*2^4, Wt*2^16, U*2^-20 -- f16 split keeps ~22 mantissa bits, f32-class accuracy).
// Chunk-phase scratch C8/Seg alias the (dead by then) inversion/AP regions.

#define OFF_MF64  0
#define OFF_YA    1572864
#define OFF_YB    3145728
#define OFF_Z     4718592
#define OFF_W0    6291456     // [3][256][512] f32 augmented [M | I], in-place GJ
#define OFF_F     7864320     // [3][32][256] f32 per-panel elementary factors
#define OFF_PIV   7962624     // [3][32] int pivots
#define OFF_AP0   10223616
#define OFF_AP1   11010048
#define OFF_BD    11796480
#define OFF_V     11800576
#define OFF_EM    14159872
#define OFF_P     14749696
#define OFF_K     16125952
#define OFF_WT    16715776
#define OFF_U     29298688
// aliases (live only during chunk phase; inversion/AP regions dead by then)
#define OFF_C8    0
#define OFF_SEG   11010048

typedef _Float16 half8 __attribute__((ext_vector_type(8)));
typedef float f32x4 __attribute__((ext_vector_type(4)));

__device__ __forceinline__ double a_entry(int i, int j){
  double base = (i < j) ? -1.0 : (((i - j) & 1) ? 1.0 : -1.0);  // (-1)^(i-j+1) for i>=j
  return base * (double)(2*i + 1);
}

// Build Mf64 = I - dt/2*A  and GJ working buffer W0 = [M_f32 | I]
__global__ void k_init(double* __restrict__ Mf64, float* __restrict__ W0){
  int s = blockIdx.y, i = blockIdx.x, j = threadIdx.x;
  double dt = (1.0 / 192.0) / (double)(1 << s);
  double m = ((i == j) ? 1.0 : 0.0) - 0.5 * dt * a_entry(i, j);
  Mf64[((size_t)s*256 + i)*256 + j] = m;
  float* w = W0 + ((size_t)s*256 + i)*512;
  w[j] = (float)m;
  w[256 + j] = (i == j) ? 1.0f : 0.0f;
}

// Panel factorization: pivoted GJ on 32-col panel, one row per thread in registers.
__global__ __launch_bounds__(256) void k_panelF(float* __restrict__ W0,
                                                float* __restrict__ Fg,
                                                int* __restrict__ pivg, int kpanel){
  int s = blockIdx.x;
  float* buf = W0 + (size_t)s*131072;
  float* Fb = Fg + (size_t)s*8192;
  int* pivb = pivg + s*32;
  int r = threadIdx.x;
  int c0 = kpanel*32;
  float row[32];
  #pragma unroll
  for (int j = 0; j < 32; j += 4){
    float4 v = *(const float4*)&buf[(size_t)r*512 + c0 + j];
    row[j] = v.x; row[j+1] = v.y; row[j+2] = v.z; row[j+3] = v.w;
  }
  __shared__ float xA[32], xB[32], prow[32], wv[4], sInv;
  __shared__ int wi[4];
  #pragma unroll
  for (int l = 0; l < 32; ++l){
    int p = c0 + l;
    float a = (r >= p) ? fabsf(row[l]) : -1.0f;
    int bi = r;
    #pragma unroll
    for (int off = 32; off > 0; off >>= 1){
      float oa = __shfl_xor(a, off);
      int ob = __shfl_xor(bi, off);
      if (oa > a || (oa == a && ob < bi)){ a = oa; bi = ob; }
    }
    if ((r & 63) == 0){ wv[r >> 6] = a; wi[r >> 6] = bi; }
    __syncthreads();
    float best = wv[0]; int piv = wi[0];
    #pragma unroll
    for (int w = 1; w < 4; ++w){
      if (wv[w] > best || (wv[w] == best && wi[w] < piv)){ best = wv[w]; piv = wi[w]; }
    }
    if (piv != p){
      if (r == p){
        #pragma unroll
        for (int j = 0; j < 32; ++j) xA[j] = row[j];
      }
      if (r == piv){
        #pragma unroll
        for (int j = 0; j < 32; ++j) xB[j] = row[j];
      }
      __syncthreads();
      if (r == p){
        #pragma unroll
        for (int j = 0; j < 32; ++j) row[j] = xB[j];
      }
      if (r == piv){
        #pragma unroll
        for (int j = 0; j < 32; ++j) row[j] = xA[j];
      }
    }
    if (r == p){
      float inv = 1.0f / row[l];
      sInv = inv;
      #pragma unroll
      for (int j = 0; j < 32; ++j){ row[j] *= inv; prow[j] = row[j]; }
    }
    __syncthreads();
    float f = (r == p) ? 0.0f : row[l];
    Fb[l*256 + r] = (r == p) ? sInv : f;
    if (r == 0) pivb[l] = piv;
    #pragma unroll
    for (int j = 0; j < 32; ++j) row[j] -= f * prow[j];
    __syncthreads();
  }
}

// Trailing update: replay the 32 elementary ops on a 32-col tile held in registers.
__global__ __launch_bounds__(256) void k_trailF(float* __restrict__ W0,
                                                const float* __restrict__ Fg,
                                                const int* __restrict__ pivg, int kpanel){
  int s = blockIdx.y;
  float* buf = W0 + (size_t)s*131072;
  const float* Fb = Fg + (size_t)s*8192;
  const int* pivb = pivg + s*32;
  int r = threadIdx.x;
  int col0 = 32*(kpanel+1) + blockIdx.x*32;
  float row[32];
  #pragma unroll
  for (int j = 0; j < 32; j += 4){
    float4 v = *(const float4*)&buf[(size_t)r*512 + col0 + j];
    row[j] = v.x; row[j+1] = v.y; row[j+2] = v.z; row[j+3] = v.w;
  }
  __shared__ float Fl[32*256];
  __shared__ float xA[32], xB[32], prow[32];
  __shared__ int pvs[32];
  #pragma unroll
  for (int i = 0; i < 32; ++i) Fl[i*256 + r] = Fb[i*256 + r];
  if (r < 32) pvs[r] = pivb[r];
  __syncthreads();
  int c0 = kpanel*32;
  for (int l = 0; l < 32; ++l){
    int p = c0 + l;
    int piv = pvs[l];
    if (piv != p){
      if (r == p){
        #pragma unroll
        for (int j = 0; j < 32; ++j) xA[j] = row[j];
      }
      if (r == piv){
        #pragma unroll
        for (int j = 0; j < 32; ++j) xB[j] = row[j];
      }
      __syncthreads();
      if (r == p){
        #pragma unroll
        for (int j = 0; j < 32; ++j) row[j] = xB[j];
      }
      if (r == piv){
        #pragma unroll
        for (int j = 0; j < 32; ++j) row[j] = xA[j];
      }
    }
    float fv = Fl[l*256 + r];
    if (r == p){
      #pragma unroll
      for (int j = 0; j < 32; ++j){ row[j] *= fv; prow[j] = row[j]; }
    }
    __syncthreads();
    if (r != p){
      #pragma unroll
      for (int j = 0; j < 32; ++j) row[j] -= fv * prow[j];
    }
    __syncthreads();
  }
  #pragma unroll
  for (int j = 0; j < 32; j += 4){
    float4 v = make_float4(row[j], row[j+1], row[j+2], row[j+3]);
    *(float4*)&buf[(size_t)r*512 + col0 + j] = v;
  }
}

__global__ void k_y0(const float* __restrict__ W, double* __restrict__ Y){
  int s = blockIdx.y, i = blockIdx.x, j = threadIdx.x;
  Y[((size_t)s*256 + i)*256 + j] = (double)W[((size_t)s*256 + i)*512 + 256 + j];
}

// Z = M @ Y  (f64)
__global__ void k_mmZ(const double* __restrict__ M, const double* __restrict__ Y,
                      double* __restrict__ Z){
  int s = blockIdx.y;
  const double* A = M + (size_t)s*65536;
  const double* B = Y + (size_t)s*65536;
  int c = threadIdx.x, r0 = blockIdx.x * 8;
  double acc[8] = {0,0,0,0,0,0,0,0};
  for (int j = 0; j < 256; ++j){
    double b = B[(size_t)j*256 + c];
    #pragma unroll
    for (int q = 0; q < 8; ++q) acc[q] += A[(size_t)(r0+q)*256 + j] * b;
  }
  #pragma unroll
  for (int q = 0; q < 8; ++q) Z[(size_t)s*65536 + (size_t)(r0+q)*256 + c] = acc[q];
}

// Yn = 2Y - Y @ Z  (Newton-Schulz step, f64)
__global__ void k_mmN(const double* __restrict__ Y, const double* __restrict__ Z,
                      double* __restrict__ Yn){
  int s = blockIdx.y;
  const double* A = Y + (size_t)s*65536;
  const double* B = Z + (size_t)s*65536;
  int c = threadIdx.x, r0 = blockIdx.x * 8;
  double acc[8] = {0,0,0,0,0,0,0,0};
  for (int j = 0; j < 256; ++j){
    double b = B[(size_t)j*256 + c];
    #pragma unroll
    for (int q = 0; q < 8; ++q) acc[q] += A[(size_t)(r0+q)*256 + j] * b;
  }
  #pragma unroll
  for (int q = 0; q < 8; ++q)
    Yn[(size_t)s*65536 + (size_t)(r0+q)*256 + c] =
      2.0 * A[(size_t)(r0+q)*256 + c] - acc[q];
}

// Ad = 2*Minv - I (f32, into AP0); Bd = Minv @ (dt*B); V row0 = Bd
__global__ void k_final(const double* __restrict__ Y, float* __restrict__ Ad,
                        float* __restrict__ Bd, float* __restrict__ V){
  int s = blockIdx.y;
  const double* Ys = Y + (size_t)s*65536;
  if (blockIdx.x < 64){
    int c = threadIdx.x, r0 = blockIdx.x * 4;
    #pragma unroll
    for (int q = 0; q < 4; ++q){
      double v = 2.0 * Ys[(size_t)(r0+q)*256 + c] - ((r0+q) == c ? 1.0 : 0.0);
      Ad[(size_t)s*65536 + (size_t)(r0+q)*256 + c] = (float)v;
    }
  } else {
    int i = threadIdx.x;
    double dt = (1.0 / 192.0) / (double)(1 << s);
    double acc = 0.0;
    for (int j = 0; j < 256; ++j){
      double bj = dt * ((j & 1) ? -1.0 : 1.0) * (double)(2*j + 1);
      acc += Ys[(size_t)i*256 + j] * bj;
    }
    float b = (float)acc;
    Bd[s*256 + i] = b;
    V[((size_t)s*768 + 0)*256 + i] = b;
  }
}

// Legendre eval matrix (last 192 rows), f64 recurrence
__global__ void k_em(float* __restrict__ em){
  int s = blockIdx.x, t = threadIdx.x;
  int T = 192 << s;
  double dt = (1.0 / 192.0) / (double)(1 << s);
  double x = 1.0 - 2.0 * ((double)(T - 192 + t) * dt);
  float* row = em + ((size_t)s*192 + t)*256;
  double p0 = 1.0, p1 = x;
  row[0] = 1.0f; row[1] = (float)x;
  for (int n = 1; n < 255; ++n){
    double p2 = ((double)(2*n+1) * x * p1 - (double)n * p0) / (double)(n+1);
    row[n+1] = (float)p2;
    p0 = p1; p1 = p2;
  }
}

// one doubling level: Pout = Pin@Pin (bx<64); V[L..2L) = Pin @ V[0..L)  (bx>=64)
__global__ void k_level(const float* __restrict__ Pin, float* __restrict__ Pout,
                        float* __restrict__ V, int L){
  int s = blockIdx.y;
  const float* A = Pin + (size_t)s*65536;
  int bx = blockIdx.x;
  if (bx < 64){
    int c = threadIdx.x, r0 = bx * 4;
    float acc[4] = {0,0,0,0};
    for (int k = 0; k < 256; ++k){
      float b = A[(size_t)k*256 + c];
      #pragma unroll
      for (int q = 0; q < 4; ++q) acc[q] += A[(size_t)(r0+q)*256 + k] * b;
    }
    #pragma unroll
    for (int q = 0; q < 4; ++q) Pout[(size_t)s*65536 + (size_t)(r0+q)*256 + c] = acc[q];
  } else {
    int j = threadIdx.x;
    if (j >= L) return;
    int r0 = (bx - 64) * 4;
    float* Vs = V + (size_t)s*768*256;
    float acc[4] = {0,0,0,0};
    for (int k = 0; k < 256; ++k){
      float v = Vs[(size_t)j*256 + k];
      #pragma unroll
      for (int q = 0; q < 4; ++q) acc[q] += A[(size_t)(r0+q)*256 + k] * v;
    }
    #pragma unroll
    for (int q = 0; q < 4; ++q) Vs[(size_t)(L+j)*256 + r0 + q] = acc[q];
  }
}

// V[128*jc + r] = A128 @ V[128*(jc-1) + r]
__global__ void k_chunk(const float* __restrict__ A128, float* __restrict__ V, int jc){
  int s = blockIdx.y;
  const float* A = A128 + (size_t)s*65536;
  float* Vs = V + (size_t)s*768*256;
  int r = threadIdx.x;          // 0..127
  int r0 = blockIdx.x * 4;
  const float* vin = Vs + (size_t)(128*(jc-1) + r)*256;
  float acc[4] = {0,0,0,0};
  for (int k = 0; k < 256; ++k){
    float v = vin[k];
    #pragma unroll
    for (int q = 0; q < 4; ++q) acc[q] += A[(size_t)(r0+q)*256 + k] * v;
  }
  #pragma unroll
  for (int q = 0; q < 4; ++q) Vs[(size_t)(128*jc + r)*256 + r0 + q] = acc[q];
}

// Wt[s][i][col] with col = (kl*2+ri)*256 + o,  k = c8+kl
__global__ void k_wt(const float* __restrict__ wr, const float* __restrict__ wi,
                     float* __restrict__ Wt, int c8){
  int s = blockIdx.x, i = blockIdx.y, tid = threadIdx.x;
  size_t srcbase = ((size_t)s*256 + i)*256;
  float* dst = Wt + ((size_t)s*256 + i)*4096;
  for (int ph = 0; ph < 16; ++ph){
    int col = ph*256 + tid;
    int kl = col >> 9, ri = (col >> 8) & 1, o = col & 255;
    const float* src = ri ? wi : wr;
    dst[col] = src[(srcbase + o)*32 + c8 + kl];
  }
}

__device__ __forceinline__ void splitf16(float x, unsigned short &h, unsigned short &l){
  _Float16 hf = (_Float16)x;
  _Float16 lf = (_Float16)(x - (float)hf);
  h = __builtin_bit_cast(unsigned short, hf);
  l = __builtin_bit_cast(unsigned short, lf);
}
__device__ __forceinline__ unsigned int pk(unsigned short a, unsigned short b){
  return (unsigned int)a | ((unsigned int)b << 16);
}

// U = V @ Wt via fp16 split MFMA.  M in {192,384,768}, N=4096, K=256.
// Block 64x64, 4 waves (2x2 of 32x32 wave-tiles), mfma_f32_16x16x32_f16.
// Scales: V*2^4, Wt*2^16 (keeps lo-halves out of f16 subnormal range), U*2^-20.
__global__ __launch_bounds__(256) void k_ugemm(const float* __restrict__ V,
                                               const float* __restrict__ Wt,
                                               float* __restrict__ U){
  int s = blockIdx.z;
  int Ts = 192 << s;
  int mt = blockIdx.y;
  if (mt*64 >= Ts) return;
  int nb = blockIdx.x * 64;
  const float* Vs = V + (size_t)s*768*256;
  const float* Bm = Wt + (size_t)s*256*4096;
  // frag-layout LDS: [kfrag=4][row=64 (+1 pad)][8 halves] as uints (2 halves/uint)
  __shared__ unsigned int Ah[4*65*4], Al[4*65*4];
  __shared__ unsigned int Bh[4*65*4], Bl[4*65*4];
  int tid = threadIdx.x;
  int lane = tid & 63;
  int w = tid >> 6;
  int m0 = (w >> 1) * 32, n0 = (w & 1) * 32;
  int ml = lane & 15, quad = lane >> 4;
  f32x4 acc[2][2];
  #pragma unroll
  for (int t = 0; t < 2; ++t)
    #pragma unroll
    for (int u = 0; u < 2; ++u) acc[t][u] = (f32x4){0.f,0.f,0.f,0.f};

  // staging index maps
  int am = tid >> 2, akf = tid & 3;          // A: row am, k-oct akf
  int bn = tid & 63, bq = tid >> 6;          // B: col bn, k-oct bq

  for (int kk = 0; kk < 8; ++kk){
    if (kk) __syncthreads();
    // ---- stage A chunk: rows mt*64.., k = kk*32 + akf*8 .. +7 ----
    {
      const float* ap = &Vs[(size_t)(mt*64 + am)*256 + kk*32 + akf*8];
      float4 a0 = *(const float4*)ap;
      float4 a1 = *(const float4*)(ap + 4);
      unsigned short h[8], l[8];
      splitf16(a0.x*16.f, h[0], l[0]); splitf16(a0.y*16.f, h[1], l[1]);
      splitf16(a0.z*16.f, h[2], l[2]); splitf16(a0.w*16.f, h[3], l[3]);
      splitf16(a1.x*16.f, h[4], l[4]); splitf16(a1.y*16.f, h[5], l[5]);
      splitf16(a1.z*16.f, h[6], l[6]); splitf16(a1.w*16.f, h[7], l[7]);
      int base = (akf*65 + am)*4;
      *(uint4*)&Ah[base] = make_uint4(pk(h[0],h[1]), pk(h[2],h[3]), pk(h[4],h[5]), pk(h[6],h[7]));
      *(uint4*)&Al[base] = make_uint4(pk(l[0],l[1]), pk(l[2],l[3]), pk(l[4],l[5]), pk(l[6],l[7]));
    }
    // ---- stage B chunk: k = kk*32 + bq*8 + j, col nb+bn ----
    {
      unsigned short h[8], l[8];
      #pragma unroll
      for (int j = 0; j < 8; ++j){
        float b = Bm[(size_t)(kk*32 + bq*8 + j)*4096 + nb + bn];
        splitf16(b*65536.f, h[j], l[j]);
      }
      int base = (bq*65 + bn)*4;
      *(uint4*)&Bh[base] = make_uint4(pk(h[0],h[1]), pk(h[2],h[3]), pk(h[4],h[5]), pk(h[6],h[7]));
      *(uint4*)&Bl[base] = make_uint4(pk(l[0],l[1]), pk(l[2],l[3]), pk(l[4],l[5]), pk(l[6],l[7]));
    }
    __syncthreads();
    // ---- frags + MFMA ----
    half8 ah[2], al[2], bh[2], bl[2];
    #pragma unroll
    for (int t = 0; t < 2; ++t){
      int idx = (quad*65 + m0 + 16*t + ml)*4;
      ah[t] = *(const half8*)&Ah[idx];
      al[t] = *(const half8*)&Al[idx];
    }
    #pragma unroll
    for (int u = 0; u < 2; ++u){
      int idx = (quad*65 + n0 + 16*u + ml)*4;
      bh[u] = *(const half8*)&Bh[idx];
      bl[u] = *(const half8*)&Bl[idx];
    }
    #pragma unroll
    for (int t = 0; t < 2; ++t)
      #pragma unroll
      for (int u = 0; u < 2; ++u){
        acc[t][u] = __builtin_amdgcn_mfma_f32_16x16x32_f16(ah[t], bh[u], acc[t][u], 0, 0, 0);
        acc[t][u] = __builtin_amdgcn_mfma_f32_16x16x32_f16(ah[t], bl[u], acc[t][u], 0, 0, 0);
        acc[t][u] = __builtin_amdgcn_mfma_f32_16x16x32_f16(al[t], bh[u], acc[t][u], 0, 0, 0);
      }
  }
  // ---- epilogue: C/D map col=lane&15, row=quad*4+r ----
  int ub = (s == 0) ? 0 : (s == 1 ? 192 : 576);
  const float unscale = 1.0f / 1048576.0f;   // 2^-20
  #pragma unroll
  for (int t = 0; t < 2; ++t)
    #pragma unroll
    for (int u = 0; u < 2; ++u){
      int row = ub + mt*64 + m0 + 16*t + quad*4;
      int col = nb + n0 + 16*u + ml;
      #pragma unroll
      for (int r = 0; r < 4; ++r)
        U[(size_t)(row + r)*4096 + col] = acc[t][u][r] * unscale;
    }
}

// ---- two-phase parallel scan ----
__global__ void k_scanA(float* __restrict__ U, float* __restrict__ Seg, int c8){
  int seg = blockIdx.x;      // 0..7
  int kl  = blockIdx.y;      // 0..7
  int s   = blockIdx.z;      // 0..2
  int k = c8 + kl;
  int T = 192 << s;
  int Ls = T >> 3;
  int m0 = seg * Ls;
  int ub = (s == 0) ? 0 : (s == 1 ? 192 : 576);
  int o = threadIdx.x;
  float* Ur = U + ((size_t)(ub + m0))*4096 + kl*512 + o;
  float th = 6.283185307179586f / (float)T;
  int im = (k * m0) % T;
  float Zr = 0.f, Zi = 0.f;
  #pragma unroll 4
  for (int i = 0; i < Ls; ++i){
    float ur = Ur[0];
    float ui = Ur[256];
    float sa, ca; __sincosf(th * (float)im, &sa, &ca);
    Zr += ca*ur + sa*ui;
    Zi += ca*ui - sa*ur;
    Ur[0] = Zr; Ur[256] = Zi;
    im += k; if (im >= T) im -= T;
    Ur += 4096;
  }
  float* Sg = Seg + (((size_t)(s*8 + kl)*8 + seg)*2)*256 + o;
  Sg[0] = Zr; Sg[256] = Zi;
}

__global__ void k_scanC(const float* __restrict__ U, const float* __restrict__ Seg,
                        float* __restrict__ C8, int c8){
  int seg = blockIdx.x, kl = blockIdx.y, s = blockIdx.z;
  int k = c8 + kl;
  int T = 192 << s;
  int Ls = T >> 3;
  int m0 = seg * Ls;
  int ub = (s == 0) ? 0 : (s == 1 ? 192 : 576);
  int o = threadIdx.x;
  float offr = 0.f, offi = 0.f;
  const float* Sg = Seg + ((size_t)(s*8 + kl)*8)*512 + o;
  for (int j = 0; j < seg; ++j){ offr += Sg[(size_t)j*512]; offi += Sg[(size_t)j*512 + 256]; }
  const float* Ur = U + ((size_t)(ub + m0))*4096 + kl*512 + o;
  float* Cb = C8 + ((size_t)kl*1344 + ub)*256 + o;
  float ckT = ((k == 0) ? 1.0f : 2.0f) / (float)T;
  float th = 6.283185307179586f / (float)T;
  int ib = (k * (192 + m0)) % T;
  #pragma unroll 4
  for (int i = 0; i < Ls; ++i){
    int m = m0 + i;
    float zr = offr + Ur[0];
    float zi = offi + Ur[256];
    float sb, cb; __sincosf(th * (float)ib, &sb, &cb);
    Cb[(size_t)(T-1-m)*256] = ckT * (zr*cb - zi*sb);
    ib += k; if (ib >= T) ib -= T;
    Ur += 4096;
  }
}

// P[row][o] (+)= sum_kl C8[kl][row][o]
__global__ void k_reduce(const float* __restrict__ C8, float* __restrict__ P, int first){
  int row = blockIdx.x;    // 0..1343
  int o = threadIdx.x;
  float a = 0.f;
  #pragma unroll
  for (int kl = 0; kl < 8; ++kl) a += C8[((size_t)kl*1344 + row)*256 + o];
  size_t idx = (size_t)row*256 + o;
  if (first) P[idx] = a; else P[idx] += a;
}

// K[to][tg] = sum_s mlpw[s] * sum_o em[s][to][o] * P[s][tg-off][o]
// 4 waves split the o-dimension, LDS combine.
__global__ __launch_bounds__(256) void k_K(const float* __restrict__ em,
                                           const float* __restrict__ P,
                                           const float* __restrict__ mlpw,
                                           float* __restrict__ K){
  int to = blockIdx.y;
  int d = threadIdx.x & 63;
  int w = threadIdx.x >> 6;
  int tg = blockIdx.x*64 + d;
  float acc = 0.f;
  for (int s = 0; s < 3; ++s){
    int T = 192 << s;
    int off = 768 - T;
    if (tg >= off){
      int ub = (s == 0) ? 0 : (s == 1 ? 192 : 576);
      const float* Pr = P + ((size_t)ub + (tg - off))*256 + w*64;
      const float* er = em + ((size_t)s*192 + to)*256 + w*64;
      float a = 0.f;
      for (int o2 = 0; o2 < 64; ++o2) a += er[o2] * Pr[o2];
      acc += mlpw[s] * a;
    }
  }
  __shared__ float red[4][64];
  red[w][d] = acc;
  __syncthreads();
  if (w == 0)
    K[(size_t)to*768 + tg] = red[0][d] + red[1][d] + red[2][d] + red[3][d];
}

// out[b][to][d] = mlp_b + sum_t K[to][t] * inputs[b][t][d]
// 4 waves split the t-dimension, LDS combine.
__global__ __launch_bounds__(256) void k_out(const float* __restrict__ K,
                                             const float* __restrict__ inp,
                                             const float* __restrict__ mlpb,
                                             float* __restrict__ out){
  int to = blockIdx.x, b = blockIdx.y;
  int d = threadIdx.x & 63;
  int w = threadIdx.x >> 6;
  const float* Kr = K + (size_t)to*768 + w*192;
  const float* ip = inp + (size_t)b*768*64 + (size_t)(w*192)*64 + d;
  float acc = 0.f;
  #pragma unroll 4
  for (int i = 0; i < 192; ++i) acc += Kr[i] * ip[(size_t)i*64];
  __shared__ float red[4][64];
  red[w][d] = acc;
  __syncthreads();
  if (w == 0)
    out[((size_t)b*192 + to)*64 + d] =
      red[0][d] + red[1][d] + red[2][d] + red[3][d] + mlpb[0];
}

extern "C" void kernel_launch(void* const* d_in, const int* in_sizes, int n_in,
                              void* d_out, int out_size, void* d_ws, size_t ws_size,
                              hipStream_t stream){
  const float* inputs  = (const float*)d_in[0];
  const float* spec_wr = (const float*)d_in[1];
  const float* spec_wi = (const float*)d_in[2];
  const float* mlp_w   = (const float*)d_in[3];
  const float* mlp_b   = (const float*)d_in[4];
  float* out = (float*)d_out;
  char* ws = (char*)d_ws;

  double* Mf64 = (double*)(ws + OFF_MF64);
  double* Ya   = (double*)(ws + OFF_YA);
  double* Yb   = (double*)(ws + OFF_YB);
  double* Zb   = (double*)(ws + OFF_Z);
  float* W0  = (float*)(ws + OFF_W0);
  float* Fg  = (float*)(ws + OFF_F);
  int*   pivg= (int*)(ws + OFF_PIV);
  float* AP0 = (float*)(ws + OFF_AP0);
  float* AP1 = (float*)(ws + OFF_AP1);
  float* Bd  = (float*)(ws + OFF_BD);
  float* V   = (float*)(ws + OFF_V);
  float* em  = (float*)(ws + OFF_EM);
  float* P   = (float*)(ws + OFF_P);
  float* Km  = (float*)(ws + OFF_K);
  float* Wt  = (float*)(ws + OFF_WT);
  float* U   = (float*)(ws + OFF_U);
  float* C8  = (float*)(ws + OFF_C8);
  float* Seg = (float*)(ws + OFF_SEG);

  k_init<<<dim3(256,3), 256, 0, stream>>>(Mf64, W0);

  for (int kp = 0; kp < 8; ++kp){
    k_panelF<<<3, 256, 0, stream>>>(W0, Fg, pivg, kp);
    k_trailF<<<dim3(15-kp,3), 256, 0, stream>>>(W0, Fg, pivg, kp);
  }
  // Minv (f32) now in W0 right half
  k_y0<<<dim3(256,3), 256, 0, stream>>>(W0, Ya);
  for (int it = 0; it < 2; ++it){
    double* yi = (it & 1) ? Yb : Ya;
    double* yo = (it & 1) ? Ya : Yb;
    k_mmZ<<<dim3(32,3), 256, 0, stream>>>(Mf64, yi, Zb);
    k_mmN<<<dim3(32,3), 256, 0, stream>>>(yi, Zb, yo);
  }
  // refined Minv in Ya (2 Newton iters: Ya->Yb->Ya)
  k_final<<<dim3(65,3), 256, 0, stream>>>(Ya, AP0, Bd, V);
  k_em<<<3, 192, 0, stream>>>(em);

  float* pin = AP0; float* pout = AP1;
  for (int L = 1; L <= 64; L <<= 1){
    k_level<<<dim3(128,3), 256, 0, stream>>>(pin, pout, V, L);
    float* t = pin; pin = pout; pout = t;
  }
  for (int jc = 1; jc <= 5; ++jc)
    k_chunk<<<dim3(64,3), 128, 0, stream>>>(pin, V, jc);

  for (int c = 0; c < 4; ++c){
    k_wt<<<dim3(3,256), 256, 0, stream>>>(spec_wr, spec_wi, Wt, c*8);
    k_ugemm<<<dim3(64,12,3), 256, 0, stream>>>(V, Wt, U);
    k_scanA<<<dim3(8,8,3), 256, 0, stream>>>(U, Seg, c*8);
    k_scanC<<<dim3(8,8,3), 256, 0, stream>>>(U, Seg, C8, c*8);
    k_reduce<<<1344, 256, 0, stream>>>(C8, P, (c == 0) ? 1 : 0);
  }
  k_K<<<dim3(12,192), 256, 0, stream>>>(em, P, mlp_w, Km);
  k_out<<<dim3(192,8), 256, 0, stream>>>(Km, inputs, mlp_b, out);
}

// Round 7
// 1119.191 us; speedup vs baseline: 2.8449x; 1.1089x over previous
//
#include <hip/hip_runtime.h>

// FiLM forward == fixed linear map K (192x768) applied to inputs (8,768,64), K rebuilt
// on-device each call from spec weights + HiPPO-LegT constants.
// Inversion: pivoted Gauss-Jordan with VIRTUAL pivoting (no row swaps; per-row used
// flags + recorded pivot sequence; right half ends as P*Minv, un-permuted in k_y0).
// Same arithmetic as classic partial pivoting -- LegT A is severely non-normal, so
// from-scratch Neumann/NS overflows f32 (round-3 lesson); GJ+f64 Newton is required.
// U-GEMM: fp16 2-way-split MFMA (16x16x32_f16, hh/hl/lh; exact 2^k scaling).
// Chunk-phase scratch C8/Seg alias the (dead by then) inversion/AP regions.

#define OFF_MF64  0
#define OFF_YA    1572864
#define OFF_YB    3145728
#define OFF_Z     4718592
#define OFF_W0    6291456     // [3][256][512] f32 augmented [M | I], in-place GJ
#define OFF_F     7864320     // [3][32][256] f32 per-panel elementary factors
#define OFF_PIV   7962624     // [3][256] int pivot sequence
#define OFF_USED  7966720     // [3][256] int used flags
#define OFF_AP0   10223616
#define OFF_AP1   11010048
#define OFF_BD    11796480
#define OFF_V     11800576
#define OFF_EM    14159872
#define OFF_P     14749696
#define OFF_K     16125952
#define OFF_WT    16715776
#define OFF_U     29298688
// aliases (live only during chunk phase; inversion/AP regions dead by then)
#define OFF_C8    0
#define OFF_SEG   11010048

typedef _Float16 half8 __attribute__((ext_vector_type(8)));
typedef float f32x4 __attribute__((ext_vector_type(4)));

__device__ __forceinline__ double a_entry(int i, int j){
  double base = (i < j) ? -1.0 : (((i - j) & 1) ? 1.0 : -1.0);  // (-1)^(i-j+1) for i>=j
  return base * (double)(2*i + 1);
}

// Build Mf64 = I - dt/2*A, GJ working buffer W0 = [M_f32 | I], zero used flags
__global__ void k_init(double* __restrict__ Mf64, float* __restrict__ W0,
                       int* __restrict__ usedg){
  int s = blockIdx.y, i = blockIdx.x, j = threadIdx.x;
  double dt = (1.0 / 192.0) / (double)(1 << s);
  double m = ((i == j) ? 1.0 : 0.0) - 0.5 * dt * a_entry(i, j);
  Mf64[((size_t)s*256 + i)*256 + j] = m;
  float* w = W0 + ((size_t)s*256 + i)*512;
  w[j] = (float)m;
  w[256 + j] = (i == j) ? 1.0f : 0.0f;
  if (j == 0) usedg[s*256 + i] = 0;
}

// Panel factorization, virtual pivoting: one row per thread in registers; argmax over
// unused rows; winner scales in place and publishes; F/pivots accumulate in registers.
__global__ __launch_bounds__(256) void k_panelF(const float* __restrict__ W0in,
                                                float* __restrict__ Fg,
                                                int* __restrict__ pivg,
                                                int* __restrict__ usedg, int kpanel){
  int s = blockIdx.x;
  const float* buf = W0in + (size_t)s*131072;
  float* Fb = Fg + (size_t)s*8192;
  int r = threadIdx.x;
  int c0 = kpanel*32;
  float row[32], freg[32];
  int pv[32];
  #pragma unroll
  for (int j = 0; j < 32; j += 4){
    float4 v = *(const float4*)&buf[(size_t)r*512 + c0 + j];
    row[j] = v.x; row[j+1] = v.y; row[j+2] = v.z; row[j+3] = v.w;
  }
  int used = usedg[s*256 + r];
  __shared__ float prow[2][32];
  __shared__ float wv[4];
  __shared__ int wi[4];
  #pragma unroll
  for (int l = 0; l < 32; ++l){
    // argmax |row[l]| over unused rows (wave butterfly + cross-wave LDS merge)
    float a = used ? -1.0f : fabsf(row[l]);
    int bi = r;
    #pragma unroll
    for (int off = 32; off > 0; off >>= 1){
      float oa = __shfl_xor(a, off);
      int ob = __shfl_xor(bi, off);
      if (oa > a || (oa == a && ob < bi)){ a = oa; bi = ob; }
    }
    if ((r & 63) == 0){ wv[r >> 6] = a; wi[r >> 6] = bi; }
    __syncthreads();
    float best = wv[0]; int piv = wi[0];
    #pragma unroll
    for (int w = 1; w < 4; ++w){
      if (wv[w] > best || (wv[w] == best && wi[w] < piv)){ best = wv[w]; piv = wi[w]; }
    }
    pv[l] = piv;
    if (r == piv){
      float inv = 1.0f / row[l];
      freg[l] = inv;
      used = 1;
      #pragma unroll
      for (int j = 0; j < 32; ++j){ row[j] *= inv; prow[l & 1][j] = row[j]; }
    }
    __syncthreads();
    float f = row[l];
    if (r != piv){
      freg[l] = f;
      #pragma unroll
      for (int j = 0; j < 32; ++j) row[j] -= f * prow[l & 1][j];
    }
    // no third barrier: prow double-buffered, wv/wi protected by the two above
  }
  #pragma unroll
  for (int l = 0; l < 32; ++l) Fb[l*256 + r] = freg[l];
  usedg[s*256 + r] = used;
  if (r == 0){
    #pragma unroll
    for (int l = 0; l < 32; ++l) pivg[s*256 + kpanel*32 + l] = pv[l];
  }
}

// Trailing update: replay the 32 elementary ops (virtual pivots) on a 32-col tile.
__global__ __launch_bounds__(256) void k_trailF(float* __restrict__ W0,
                                                const float* __restrict__ Fg,
                                                const int* __restrict__ pivg, int kpanel){
  int s = blockIdx.y;
  float* buf = W0 + (size_t)s*131072;
  const float* Fb = Fg + (size_t)s*8192;
  const int* pivb = pivg + s*256 + kpanel*32;
  int r = threadIdx.x;
  int col0 = 32*(kpanel+1) + blockIdx.x*32;
  float row[32], f[32];
  #pragma unroll
  for (int j = 0; j < 32; j += 4){
    float4 v = *(const float4*)&buf[(size_t)r*512 + col0 + j];
    row[j] = v.x; row[j+1] = v.y; row[j+2] = v.z; row[j+3] = v.w;
  }
  #pragma unroll
  for (int l = 0; l < 32; ++l) f[l] = Fb[l*256 + r];
  __shared__ float prow[2][32];
  __shared__ int pvs[32];
  if (r < 32) pvs[r] = pivb[r];
  __syncthreads();
  #pragma unroll
  for (int l = 0; l < 32; ++l){
    int piv = pvs[l];
    if (r == piv){
      #pragma unroll
      for (int j = 0; j < 32; ++j){ row[j] *= f[l]; prow[l & 1][j] = row[j]; }
    }
    __syncthreads();
    if (r != piv){
      #pragma unroll
      for (int j = 0; j < 32; ++j) row[j] -= f[l] * prow[l & 1][j];
    }
  }
  #pragma unroll
  for (int j = 0; j < 32; j += 4){
    float4 v = make_float4(row[j], row[j+1], row[j+2], row[j+3]);
    *(float4*)&buf[(size_t)r*512 + col0 + j] = v;
  }
}

// Y[l] = W0right[piv_l]  (un-permute: right half holds P*Minv)
__global__ void k_y0(const float* __restrict__ W, const int* __restrict__ pivg,
                     double* __restrict__ Y){
  int s = blockIdx.y, i = blockIdx.x, j = threadIdx.x;
  int p = pivg[s*256 + i];
  Y[((size_t)s*256 + i)*256 + j] = (double)W[((size_t)s*256 + p)*512 + 256 + j];
}

// Z = M @ Y  (f64)
__global__ void k_mmZ(const double* __restrict__ M, const double* __restrict__ Y,
                      double* __restrict__ Z){
  int s = blockIdx.y;
  const double* A = M + (size_t)s*65536;
  const double* B = Y + (size_t)s*65536;
  int c = threadIdx.x, r0 = blockIdx.x * 8;
  double acc[8] = {0,0,0,0,0,0,0,0};
  for (int j = 0; j < 256; ++j){
    double b = B[(size_t)j*256 + c];
    #pragma unroll
    for (int q = 0; q < 8; ++q) acc[q] += A[(size_t)(r0+q)*256 + j] * b;
  }
  #pragma unroll
  for (int q = 0; q < 8; ++q) Z[(size_t)s*65536 + (size_t)(r0+q)*256 + c] = acc[q];
}

// Yn = 2Y - Y @ Z  (Newton-Schulz step, f64)
__global__ void k_mmN(const double* __restrict__ Y, const double* __restrict__ Z,
                      double* __restrict__ Yn){
  int s = blockIdx.y;
  const double* A = Y + (size_t)s*65536;
  const double* B = Z + (size_t)s*65536;
  int c = threadIdx.x, r0 = blockIdx.x * 8;
  double acc[8] = {0,0,0,0,0,0,0,0};
  for (int j = 0; j < 256; ++j){
    double b = B[(size_t)j*256 + c];
    #pragma unroll
    for (int q = 0; q < 8; ++q) acc[q] += A[(size_t)(r0+q)*256 + j] * b;
  }
  #pragma unroll
  for (int q = 0; q < 8; ++q)
    Yn[(size_t)s*65536 + (size_t)(r0+q)*256 + c] =
      2.0 * A[(size_t)(r0+q)*256 + c] - acc[q];
}

// Ad = 2*Minv - I (f32, into AP0); Bd = Minv @ (dt*B); V row0 = Bd
__global__ void k_final(const double* __restrict__ Y, float* __restrict__ Ad,
                        float* __restrict__ Bd, float* __restrict__ V){
  int s = blockIdx.y;
  const double* Ys = Y + (size_t)s*65536;
  if (blockIdx.x < 64){
    int c = threadIdx.x, r0 = blockIdx.x * 4;
    #pragma unroll
    for (int q = 0; q < 4; ++q){
      double v = 2.0 * Ys[(size_t)(r0+q)*256 + c] - ((r0+q) == c ? 1.0 : 0.0);
      Ad[(size_t)s*65536 + (size_t)(r0+q)*256 + c] = (float)v;
    }
  } else {
    int i = threadIdx.x;
    double dt = (1.0 / 192.0) / (double)(1 << s);
    double acc = 0.0;
    for (int j = 0; j < 256; ++j){
      double bj = dt * ((j & 1) ? -1.0 : 1.0) * (double)(2*j + 1);
      acc += Ys[(size_t)i*256 + j] * bj;
    }
    float b = (float)acc;
    Bd[s*256 + i] = b;
    V[((size_t)s*768 + 0)*256 + i] = b;
  }
}

// Legendre eval matrix (last 192 rows), f64 recurrence
__global__ void k_em(float* __restrict__ em){
  int s = blockIdx.x, t = threadIdx.x;
  int T = 192 << s;
  double dt = (1.0 / 192.0) / (double)(1 << s);
  double x = 1.0 - 2.0 * ((double)(T - 192 + t) * dt);
  float* row = em + ((size_t)s*192 + t)*256;
  double p0 = 1.0, p1 = x;
  row[0] = 1.0f; row[1] = (float)x;
  for (int n = 1; n < 255; ++n){
    double p2 = ((double)(2*n+1) * x * p1 - (double)n * p0) / (double)(n+1);
    row[n+1] = (float)p2;
    p0 = p1; p1 = p2;
  }
}

// one doubling level: Pout = Pin@Pin (bx<64); V[L..2L) = Pin @ V[0..L)  (bx>=64)
__global__ void k_level(const float* __restrict__ Pin, float* __restrict__ Pout,
                        float* __restrict__ V, int L){
  int s = blockIdx.y;
  const float* A = Pin + (size_t)s*65536;
  int bx = blockIdx.x;
  if (bx < 64){
    int c = threadIdx.x, r0 = bx * 4;
    float acc[4] = {0,0,0,0};
    for (int k = 0; k < 256; ++k){
      float b = A[(size_t)k*256 + c];
      #pragma unroll
      for (int q = 0; q < 4; ++q) acc[q] += A[(size_t)(r0+q)*256 + k] * b;
    }
    #pragma unroll
    for (int q = 0; q < 4; ++q) Pout[(size_t)s*65536 + (size_t)(r0+q)*256 + c] = acc[q];
  } else {
    int j = threadIdx.x;
    if (j >= L) return;
    int r0 = (bx - 64) * 4;
    float* Vs = V + (size_t)s*768*256;
    float acc[4] = {0,0,0,0};
    for (int k = 0; k < 256; ++k){
      float v = Vs[(size_t)j*256 + k];
      #pragma unroll
      for (int q = 0; q < 4; ++q) acc[q] += A[(size_t)(r0+q)*256 + k] * v;
    }
    #pragma unroll
    for (int q = 0; q < 4; ++q) Vs[(size_t)(L+j)*256 + r0 + q] = acc[q];
  }
}

// V[128*jc + r] = A128 @ V[128*(jc-1) + r]
__global__ void k_chunk(const float* __restrict__ A128, float* __restrict__ V, int jc){
  int s = blockIdx.y;
  const float* A = A128 + (size_t)s*65536;
  float* Vs = V + (size_t)s*768*256;
  int r = threadIdx.x;          // 0..127
  int r0 = blockIdx.x * 4;
  const float* vin = Vs + (size_t)(128*(jc-1) + r)*256;
  float acc[4] = {0,0,0,0};
  for (int k = 0; k < 256; ++k){
    float v = vin[k];
    #pragma unroll
    for (int q = 0; q < 4; ++q) acc[q] += A[(size_t)(r0+q)*256 + k] * v;
  }
  #pragma unroll
  for (int q = 0; q < 4; ++q) Vs[(size_t)(128*jc + r)*256 + r0 + q] = acc[q];
}

// Wt[s][i][col] with col = (kl*2+ri)*256 + o,  k = c8+kl
__global__ void k_wt(const float* __restrict__ wr, const float* __restrict__ wi,
                     float* __restrict__ Wt, int c8){
  int s = blockIdx.x, i = blockIdx.y, tid = threadIdx.x;
  size_t srcbase = ((size_t)s*256 + i)*256;
  float* dst = Wt + ((size_t)s*256 + i)*4096;
  for (int ph = 0; ph < 16; ++ph){
    int col = ph*256 + tid;
    int kl = col >> 9, ri = (col >> 8) & 1, o = col & 255;
    const float* src = ri ? wi : wr;
    dst[col] = src[(srcbase + o)*32 + c8 + kl];
  }
}

__device__ __forceinline__ void splitf16(float x, unsigned short &h, unsigned short &l){
  _Float16 hf = (_Float16)x;
  _Float16 lf = (_Float16)(x - (float)hf);
  h = __builtin_bit_cast(unsigned short, hf);
  l = __builtin_bit_cast(unsigned short, lf);
}
__device__ __forceinline__ unsigned int pk(unsigned short a, unsigned short b){
  return (unsigned int)a | ((unsigned int)b << 16);
}

// U = V @ Wt via fp16 split MFMA.  M in {192,384,768}, N=4096, K=256.
// Block 64x64, 4 waves (2x2 of 32x32 wave-tiles), mfma_f32_16x16x32_f16.
// Scales: V*2^4, Wt*2^16 (keeps lo-halves out of f16 subnormal range), U*2^-20.
__global__ __launch_bounds__(256) void k_ugemm(const float* __restrict__ V,
                                               const float* __restrict__ Wt,
                                               float* __restrict__ U){
  int s = blockIdx.z;
  int Ts = 192 << s;
  int mt = blockIdx.y;
  if (mt*64 >= Ts) return;
  int nb = blockIdx.x * 64;
  const float* Vs = V + (size_t)s*768*256;
  const float* Bm = Wt + (size_t)s*256*4096;
  __shared__ unsigned int Ah[4*65*4], Al[4*65*4];
  __shared__ unsigned int Bh[4*65*4], Bl[4*65*4];
  int tid = threadIdx.x;
  int lane = tid & 63;
  int w = tid >> 6;
  int m0 = (w >> 1) * 32, n0 = (w & 1) * 32;
  int ml = lane & 15, quad = lane >> 4;
  f32x4 acc[2][2];
  #pragma unroll
  for (int t = 0; t < 2; ++t)
    #pragma unroll
    for (int u = 0; u < 2; ++u) acc[t][u] = (f32x4){0.f,0.f,0.f,0.f};

  int am = tid >> 2, akf = tid & 3;
  int bn = tid & 63, bq = tid >> 6;

  for (int kk = 0; kk < 8; ++kk){
    if (kk) __syncthreads();
    {
      const float* ap = &Vs[(size_t)(mt*64 + am)*256 + kk*32 + akf*8];
      float4 a0 = *(const float4*)ap;
      float4 a1 = *(const float4*)(ap + 4);
      unsigned short h[8], l[8];
      splitf16(a0.x*16.f, h[0], l[0]); splitf16(a0.y*16.f, h[1], l[1]);
      splitf16(a0.z*16.f, h[2], l[2]); splitf16(a0.w*16.f, h[3], l[3]);
      splitf16(a1.x*16.f, h[4], l[4]); splitf16(a1.y*16.f, h[5], l[5]);
      splitf16(a1.z*16.f, h[6], l[6]); splitf16(a1.w*16.f, h[7], l[7]);
      int base = (akf*65 + am)*4;
      *(uint4*)&Ah[base] = make_uint4(pk(h[0],h[1]), pk(h[2],h[3]), pk(h[4],h[5]), pk(h[6],h[7]));
      *(uint4*)&Al[base] = make_uint4(pk(l[0],l[1]), pk(l[2],l[3]), pk(l[4],l[5]), pk(l[6],l[7]));
    }
    {
      unsigned short h[8], l[8];
      #pragma unroll
      for (int j = 0; j < 8; ++j){
        float b = Bm[(size_t)(kk*32 + bq*8 + j)*4096 + nb + bn];
        splitf16(b*65536.f, h[j], l[j]);
      }
      int base = (bq*65 + bn)*4;
      *(uint4*)&Bh[base] = make_uint4(pk(h[0],h[1]), pk(h[2],h[3]), pk(h[4],h[5]), pk(h[6],h[7]));
      *(uint4*)&Bl[base] = make_uint4(pk(l[0],l[1]), pk(l[2],l[3]), pk(l[4],l[5]), pk(l[6],l[7]));
    }
    __syncthreads();
    half8 ah[2], al[2], bh[2], bl[2];
    #pragma unroll
    for (int t = 0; t < 2; ++t){
      int idx = (quad*65 + m0 + 16*t + ml)*4;
      ah[t] = *(const half8*)&Ah[idx];
      al[t] = *(const half8*)&Al[idx];
    }
    #pragma unroll
    for (int u = 0; u < 2; ++u){
      int idx = (quad*65 + n0 + 16*u + ml)*4;
      bh[u] = *(const half8*)&Bh[idx];
      bl[u] = *(const half8*)&Bl[idx];
    }
    #pragma unroll
    for (int t = 0; t < 2; ++t)
      #pragma unroll
      for (int u = 0; u < 2; ++u){
        acc[t][u] = __builtin_amdgcn_mfma_f32_16x16x32_f16(ah[t], bh[u], acc[t][u], 0, 0, 0);
        acc[t][u] = __builtin_amdgcn_mfma_f32_16x16x32_f16(ah[t], bl[u], acc[t][u], 0, 0, 0);
        acc[t][u] = __builtin_amdgcn_mfma_f32_16x16x32_f16(al[t], bh[u], acc[t][u], 0, 0, 0);
      }
  }
  int ub = (s == 0) ? 0 : (s == 1 ? 192 : 576);
  const float unscale = 1.0f / 1048576.0f;   // 2^-20
  #pragma unroll
  for (int t = 0; t < 2; ++t)
    #pragma unroll
    for (int u = 0; u < 2; ++u){
      int row = ub + mt*64 + m0 + 16*t + quad*4;
      int col = nb + n0 + 16*u + ml;
      #pragma unroll
      for (int r = 0; r < 4; ++r)
        U[(size_t)(row + r)*4096 + col] = acc[t][u][r] * unscale;
    }
}

// ---- two-phase parallel scan ----
__global__ void k_scanA(float* __restrict__ U, float* __restrict__ Seg, int c8){
  int seg = blockIdx.x;      // 0..7
  int kl  = blockIdx.y;      // 0..7
  int s   = blockIdx.z;      // 0..2
  int k = c8 + kl;
  int T = 192 << s;
  int Ls = T >> 3;
  int m0 = seg * Ls;
  int ub = (s == 0) ? 0 : (s == 1 ? 192 : 576);
  int o = threadIdx.x;
  float* Ur = U + ((size_t)(ub + m0))*4096 + kl*512 + o;
  float th = 6.283185307179586f / (float)T;
  int im = (k * m0) % T;
  float Zr = 0.f, Zi = 0.f;
  #pragma unroll 4
  for (int i = 0; i < Ls; ++i){
    float ur = Ur[0];
    float ui = Ur[256];
    float sa, ca; __sincosf(th * (float)im, &sa, &ca);
    Zr += ca*ur + sa*ui;
    Zi += ca*ui - sa*ur;
    Ur[0] = Zr; Ur[256] = Zi;
    im += k; if (im >= T) im -= T;
    Ur += 4096;
  }
  float* Sg = Seg + (((size_t)(s*8 + kl)*8 + seg)*2)*256 + o;
  Sg[0] = Zr; Sg[256] = Zi;
}

__global__ void k_scanC(const float* __restrict__ U, const float* __restrict__ Seg,
                        float* __restrict__ C8, int c8){
  int seg = blockIdx.x, kl = blockIdx.y, s = blockIdx.z;
  int k = c8 + kl;
  int T = 192 << s;
  int Ls = T >> 3;
  int m0 = seg * Ls;
  int ub = (s == 0) ? 0 : (s == 1 ? 192 : 576);
  int o = threadIdx.x;
  float offr = 0.f, offi = 0.f;
  const float* Sg = Seg + ((size_t)(s*8 + kl)*8)*512 + o;
  for (int j = 0; j < seg; ++j){ offr += Sg[(size_t)j*512]; offi += Sg[(size_t)j*512 + 256]; }
  const float* Ur = U + ((size_t)(ub + m0))*4096 + kl*512 + o;
  float* Cb = C8 + ((size_t)kl*1344 + ub)*256 + o;
  float ckT = ((k == 0) ? 1.0f : 2.0f) / (float)T;
  float th = 6.283185307179586f / (float)T;
  int ib = (k * (192 + m0)) % T;
  #pragma unroll 4
  for (int i = 0; i < Ls; ++i){
    int m = m0 + i;
    float zr = offr + Ur[0];
    float zi = offi + Ur[256];
    float sb, cb; __sincosf(th * (float)ib, &sb, &cb);
    Cb[(size_t)(T-1-m)*256] = ckT * (zr*cb - zi*sb);
    ib += k; if (ib >= T) ib -= T;
    Ur += 4096;
  }
}

// P[row][o] (+)= sum_kl C8[kl][row][o]
__global__ void k_reduce(const float* __restrict__ C8, float* __restrict__ P, int first){
  int row = blockIdx.x;    // 0..1343
  int o = threadIdx.x;
  float a = 0.f;
  #pragma unroll
  for (int kl = 0; kl < 8; ++kl) a += C8[((size_t)kl*1344 + row)*256 + o];
  size_t idx = (size_t)row*256 + o;
  if (first) P[idx] = a; else P[idx] += a;
}

// K[to][tg] = sum_s mlpw[s] * sum_o em[s][to][o] * P[s][tg-off][o]
__global__ __launch_bounds__(256) void k_K(const float* __restrict__ em,
                                           const float* __restrict__ P,
                                           const float* __restrict__ mlpw,
                                           float* __restrict__ K){
  int to = blockIdx.y;
  int d = threadIdx.x & 63;
  int w = threadIdx.x >> 6;
  int tg = blockIdx.x*64 + d;
  float acc = 0.f;
  for (int s = 0; s < 3; ++s){
    int T = 192 << s;
    int off = 768 - T;
    if (tg >= off){
      int ub = (s == 0) ? 0 : (s == 1 ? 192 : 576);
      const float* Pr = P + ((size_t)ub + (tg - off))*256 + w*64;
      const float* er = em + ((size_t)s*192 + to)*256 + w*64;
      float a = 0.f;
      for (int o2 = 0; o2 < 64; ++o2) a += er[o2] * Pr[o2];
      acc += mlpw[s] * a;
    }
  }
  __shared__ float red[4][64];
  red[w][d] = acc;
  __syncthreads();
  if (w == 0)
    K[(size_t)to*768 + tg] = red[0][d] + red[1][d] + red[2][d] + red[3][d];
}

// out[b][to][d] = mlp_b + sum_t K[to][t] * inputs[b][t][d]
__global__ __launch_bounds__(256) void k_out(const float* __restrict__ K,
                                             const float* __restrict__ inp,
                                             const float* __restrict__ mlpb,
                                             float* __restrict__ out){
  int to = blockIdx.x, b = blockIdx.y;
  int d = threadIdx.x & 63;
  int w = threadIdx.x >> 6;
  const float* Kr = K + (size_t)to*768 + w*192;
  const float* ip = inp + (size_t)b*768*64 + (size_t)(w*192)*64 + d;
  float acc = 0.f;
  #pragma unroll 4
  for (int i = 0; i < 192; ++i) acc += Kr[i] * ip[(size_t)i*64];
  __shared__ float red[4][64];
  red[w][d] = acc;
  __syncthreads();
  if (w == 0)
    out[((size_t)b*192 + to)*64 + d] =
      red[0][d] + red[1][d] + red[2][d] + red[3][d] + mlpb[0];
}

extern "C" void kernel_launch(void* const* d_in, const int* in_sizes, int n_in,
                              void* d_out, int out_size, void* d_ws, size_t ws_size,
                              hipStream_t stream){
  const float* inputs  = (const float*)d_in[0];
  const float* spec_wr = (const float*)d_in[1];
  const float* spec_wi = (const float*)d_in[2];
  const float* mlp_w   = (const float*)d_in[3];
  const float* mlp_b   = (const float*)d_in[4];
  float* out = (float*)d_out;
  char* ws = (char*)d_ws;

  double* Mf64 = (double*)(ws + OFF_MF64);
  double* Ya   = (double*)(ws + OFF_YA);
  double* Yb   = (double*)(ws + OFF_YB);
  double* Zb   = (double*)(ws + OFF_Z);
  float* W0  = (float*)(ws + OFF_W0);
  float* Fg  = (float*)(ws + OFF_F);
  int*   pivg= (int*)(ws + OFF_PIV);
  int*   usedg=(int*)(ws + OFF_USED);
  float* AP0 = (float*)(ws + OFF_AP0);
  float* AP1 = (float*)(ws + OFF_AP1);
  float* Bd  = (float*)(ws + OFF_BD);
  float* V   = (float*)(ws + OFF_V);
  float* em  = (float*)(ws + OFF_EM);
  float* P   = (float*)(ws + OFF_P);
  float* Km  = (float*)(ws + OFF_K);
  float* Wt  = (float*)(ws + OFF_WT);
  float* U   = (float*)(ws + OFF_U);
  float* C8  = (float*)(ws + OFF_C8);
  float* Seg = (float*)(ws + OFF_SEG);

  k_init<<<dim3(256,3), 256, 0, stream>>>(Mf64, W0, usedg);

  for (int kp = 0; kp < 8; ++kp){
    k_panelF<<<3, 256, 0, stream>>>(W0, Fg, pivg, usedg, kp);
    k_trailF<<<dim3(15-kp,3), 256, 0, stream>>>(W0, Fg, pivg, kp);
  }
  // right half now P*Minv; un-permute while lifting to f64
  k_y0<<<dim3(256,3), 256, 0, stream>>>(W0, pivg, Ya);
  for (int it = 0; it < 2; ++it){
    double* yi = (it & 1) ? Yb : Ya;
    double* yo = (it & 1) ? Ya : Yb;
    k_mmZ<<<dim3(32,3), 256, 0, stream>>>(Mf64, yi, Zb);
    k_mmN<<<dim3(32,3), 256, 0, stream>>>(yi, Zb, yo);
  }
  // refined Minv in Ya (2 Newton iters: Ya->Yb->Ya)
  k_final<<<dim3(65,3), 256, 0, stream>>>(Ya, AP0, Bd, V);
  k_em<<<3, 192, 0, stream>>>(em);

  float* pin = AP0; float* pout = AP1;
  for (int L = 1; L <= 64; L <<= 1){
    k_level<<<dim3(128,3), 256, 0, stream>>>(pin, pout, V, L);
    float* t = pin; pin = pout; pout = t;
  }
  for (int jc = 1; jc <= 5; ++jc)
    k_chunk<<<dim3(64,3), 128, 0, stream>>>(pin, V, jc);

  for (int c = 0; c < 4; ++c){
    k_wt<<<dim3(3,256), 256, 0, stream>>>(spec_wr, spec_wi, Wt, c*8);
    k_ugemm<<<dim3(64,12,3), 256, 0, stream>>>(V, Wt, U);
    k_scanA<<<dim3(8,8,3), 256, 0, stream>>>(U, Seg, c*8);
    k_scanC<<<dim3(8,8,3), 256, 0, stream>>>(U, Seg, C8, c*8);
    k_reduce<<<1344, 256, 0, stream>>>(C8, P, (c == 0) ? 1 : 0);
  }
  k_K<<<dim3(12,192), 256, 0, stream>>>(em, P, mlp_w, Km);
  k_out<<<dim3(192,8), 256, 0, stream>>>(Km, inputs, mlp_b, out);
}